// Round 8
// baseline (1733.572 us; speedup 1.0000x reference)
//
#include <hip/hip_runtime.h>
#include <hip/hip_bf16.h>
#include <math.h>

#define NROWS   262144
#define BM      32
#define THREADS 256
#define LDSB_A  (32768 + 1024)
#define LDSB_B  32768

using bf16x8 = __attribute__((ext_vector_type(8))) short;
using s16x4  = __attribute__((ext_vector_type(4))) short;
using f32x4  = __attribute__((ext_vector_type(4))) float;

__device__ __forceinline__ short f2bf(float f) {
  __hip_bfloat16 h = __float2bfloat16(f);
  return __builtin_bit_cast(short, h);
}
__device__ __forceinline__ float bf2f(short s) {
  __hip_bfloat16 h = __builtin_bit_cast(__hip_bfloat16, s);
  return __bfloat162float(h);
}
// XOR-swizzled byte offset into a [32][256] bf16 LDS tile (row stride 512B)
__device__ __forceinline__ int swz(int row, int col) {
  return row * 512 + ((col * 2) ^ ((row & 7) << 4));
}

__device__ __forceinline__ float red16(float p) {
  p += __shfl_xor(p, 1, 64);
  p += __shfl_xor(p, 2, 64);
  p += __shfl_xor(p, 4, 64);
  p += __shfl_xor(p, 8, 64);
  return p;
}

// stage a [32][256] f32 global tile -> swizzled bf16 LDS tile
__device__ __forceinline__ void stage_tile(char* __restrict__ buf,
                                           const float* __restrict__ g, int tid) {
#pragma unroll 2
  for (int it = 0; it < 8; ++it) {
    int idx = it * THREADS + tid;          // 0..2047 float4 slots
    int r = idx >> 6;                       // 0..31
    int c = (idx & 63) << 2;
    float4 v = *(const float4*)(g + r * 256 + c);
    s16x4 o;
    o[0] = f2bf(v.x); o[1] = f2bf(v.y); o[2] = f2bf(v.z); o[3] = f2bf(v.w);
    *(s16x4*)(buf + swz(r, c)) = o;
  }
}

// C[32 rows x NF*16 cols] += A_lds[32 x 256] @ WT[cols][Kw] (B pre-transposed bf16)
template <int MF, int NF>
__device__ __forceinline__ void gemmT(const char* __restrict__ Abuf,
                                      const short* __restrict__ WT, int Kw,
                                      int col0, int koff, int li, int hi,
                                      f32x4 (&acc)[MF][NF]) {
  const short* wp[NF];
#pragma unroll
  for (int n = 0; n < NF; ++n)
    wp[n] = WT + (size_t)(col0 + 16 * n + li) * Kw + koff + hi * 8;
#pragma unroll 2
  for (int kk = 0; kk < 256; kk += 32) {
    int ka = kk + hi * 8;
    bf16x8 b[NF];
#pragma unroll
    for (int n = 0; n < NF; ++n) b[n] = *(const bf16x8*)(wp[n] + kk);
    bf16x8 a[MF];
#pragma unroll
    for (int m = 0; m < MF; ++m)
      a[m] = *(const bf16x8*)(Abuf + swz(16 * m + li, ka));
#pragma unroll
    for (int m = 0; m < MF; ++m)
#pragma unroll
      for (int n = 0; n < NF; ++n)
        acc[m][n] = __builtin_amdgcn_mfma_f32_16x16x32_bf16(a[m], b[n], acc[m][n], 0, 0, 0);
  }
}

// transpose + bf16-convert all weights (Wq pre-scaled by 1/sqrt(DH)):
// WqT,WkT,WvT,WoT: [256][256]; W1T: [1024][256]; W2T: [256][1024]
__global__ void prep(const float* __restrict__ Wq, const float* __restrict__ Wk,
                     const float* __restrict__ Wv, const float* __restrict__ Wo,
                     const float* __restrict__ W1, const float* __restrict__ W2,
                     short* __restrict__ wt) {
  int idx = blockIdx.x * blockDim.x + threadIdx.x;  // 0..786431
  if (idx < 262144) {
    int m = idx >> 16;
    const float* W = (m == 0) ? Wq : (m == 1) ? Wk : (m == 2) ? Wv : Wo;
    float s = (m == 0) ? 0.17677669529663687f : 1.0f;
    int l = idx & 65535;
    int n = l >> 8, k = l & 255;
    wt[idx] = f2bf(W[k * 256 + n] * s);
  } else if (idx < 524288) {
    int l = idx - 262144;
    int n = l >> 8, k = l & 255;
    wt[idx] = f2bf(W1[k * 1024 + n]);
  } else {
    int l = idx - 524288;
    int n = l >> 10, k = l & 1023;
    wt[idx] = f2bf(W2[k * 256 + n]);
  }
}

// ================= kernel A: attention + O-proj + LN1 -> h (bf16) =================
__global__ __launch_bounds__(THREADS, 4)
void attn_ln1(const float* __restrict__ x, const float* __restrict__ sx,
              const float* __restrict__ dx,
              const float* __restrict__ bq, const float* __restrict__ bv,
              const float* __restrict__ bo,
              const float* __restrict__ g1, const float* __restrict__ be1,
              const short* __restrict__ wt, short* __restrict__ hout) {
  extern __shared__ char sm[];
  char* Tbuf = sm;              // x tile -> src tile -> LN1 scratch
  char* Cbuf = sm + 16384;      // dst tile -> ctx -> h stage
  float* sc    = (float*)(sm + 32768);   // [4 waves][2 heads][32 rows]
  float* scrT  = (float*)Tbuf;
  float* scr2T = (float*)(Tbuf + 2048);

  const short* WqT = wt;
  const short* WkT = wt + 65536;
  const short* WvT = wt + 131072;
  const short* WoT = wt + 196608;

  const int tid  = threadIdx.x;
  const int w    = tid >> 6;              // 0..3
  const int lane = tid & 63;
  const int li   = lane & 15;
  const int hi   = lane >> 4;
  const int cw   = w * 64;                // wave col slice (2 heads)
  const size_t row0 = (size_t)blockIdx.x * BM;

  const float* xt = x  + row0 * 256;
  const float* st = sx + row0 * 256;
  const float* dt = dx + row0 * 256;

  // ---- P0: stage x ----
  stage_tile(Tbuf, xt, tid);
  __syncthreads();

  // ---- P1: stage dst -> Cbuf; Q gemm (Tbuf, Wq pre-scaled) ----
  f32x4 qa[2][4];
#pragma unroll
  for (int m = 0; m < 2; ++m)
#pragma unroll
    for (int n = 0; n < 4; ++n) qa[m][n] = (f32x4){0.f, 0.f, 0.f, 0.f};
  stage_tile(Cbuf, dt, tid);
  gemmT<2, 4>(Tbuf, WqT, 256, cw, 0, li, hi, qa);
  {
    const float scl = 0.17677669529663687f;
#pragma unroll
    for (int n = 0; n < 4; ++n) {
      float bqn = bq[cw + 16 * n + li] * scl;
#pragma unroll
      for (int m = 0; m < 2; ++m)
#pragma unroll
        for (int j = 0; j < 4; ++j) qa[m][n][j] += bqn;
    }
  }
  __syncthreads();

  // ---- P2: K_dst gemms (per head) -> scores; stage src -> Tbuf ----
  {
    float p[2][2][4];
#pragma unroll
    for (int hh = 0; hh < 2; ++hh) {
      f32x4 ka[2][2];
#pragma unroll
      for (int m = 0; m < 2; ++m)
#pragma unroll
        for (int n = 0; n < 2; ++n) ka[m][n] = (f32x4){0.f, 0.f, 0.f, 0.f};
      gemmT<2, 2>(Cbuf, WkT, 256, cw + 32 * hh, 0, li, hi, ka);
#pragma unroll
      for (int m = 0; m < 2; ++m)
#pragma unroll
        for (int j = 0; j < 4; ++j)
          p[hh][m][j] = qa[m][2 * hh][j] * ka[m][0][j] + qa[m][2 * hh + 1][j] * ka[m][1][j];
    }
    stage_tile(Tbuf, st, tid);
#pragma unroll
    for (int hh = 0; hh < 2; ++hh)
#pragma unroll
      for (int m = 0; m < 2; ++m)
#pragma unroll
        for (int j = 0; j < 4; ++j) {
          float pr = red16(p[hh][m][j]);
          if (li == 0) sc[(w * 2 + hh) * 32 + 16 * m + 4 * hi + j] = pr;
        }
  }
  __syncthreads();

  // ---- P3: K_src gemms -> weights in sc[]; V_src; V_dst; combine ----
#pragma unroll
  for (int hh = 0; hh < 2; ++hh) {
    f32x4 ka[2][2];
#pragma unroll
    for (int m = 0; m < 2; ++m)
#pragma unroll
      for (int n = 0; n < 2; ++n) ka[m][n] = (f32x4){0.f, 0.f, 0.f, 0.f};
    gemmT<2, 2>(Tbuf, WkT, 256, cw + 32 * hh, 0, li, hi, ka);
#pragma unroll
    for (int m = 0; m < 2; ++m)
#pragma unroll
      for (int j = 0; j < 4; ++j) {
        float ps = red16(qa[m][2 * hh][j] * ka[m][0][j] + qa[m][2 * hh + 1][j] * ka[m][1][j]);
        int r = 16 * m + 4 * hi + j;
        float pdv = sc[(w * 2 + hh) * 32 + r];        // lockstep-safe
        float awv = 1.f / (1.f + expf(pdv - ps));      // weight on V_src
        if (li == 0) sc[(w * 2 + hh) * 32 + r] = awv;
      }
  }
  f32x4 vs[2][4];
#pragma unroll
  for (int m = 0; m < 2; ++m)
#pragma unroll
    for (int n = 0; n < 4; ++n) vs[m][n] = (f32x4){0.f, 0.f, 0.f, 0.f};
  gemmT<2, 4>(Tbuf, WvT, 256, cw, 0, li, hi, vs);
#pragma unroll
  for (int hh = 0; hh < 2; ++hh) {
    f32x4 vd[2][2];
#pragma unroll
    for (int m = 0; m < 2; ++m)
#pragma unroll
      for (int n = 0; n < 2; ++n) vd[m][n] = (f32x4){0.f, 0.f, 0.f, 0.f};
    gemmT<2, 2>(Cbuf, WvT, 256, cw + 32 * hh, 0, li, hi, vd);
#pragma unroll
    for (int n = 0; n < 2; ++n) {
      float bvn = bv[cw + 32 * hh + 16 * n + li];
#pragma unroll
      for (int m = 0; m < 2; ++m)
#pragma unroll
        for (int j = 0; j < 4; ++j) {
          float a = sc[(w * 2 + hh) * 32 + 16 * m + 4 * hi + j];
          vs[m][2 * hh + n][j] = a * vs[m][2 * hh + n][j] + (1.f - a) * vd[m][n][j] + bvn;
        }
    }
  }
  __syncthreads();

  // ---- P4: ctx -> Cbuf (bf16, swizzled) ----
#pragma unroll
  for (int m = 0; m < 2; ++m)
#pragma unroll
    for (int n = 0; n < 4; ++n)
#pragma unroll
      for (int j = 0; j < 4; ++j)
        *(short*)(Cbuf + swz(16 * m + 4 * hi + j, cw + 16 * n + li)) = f2bf(vs[m][n][j]);
  __syncthreads();

  // ---- P5: O-proj gemm + bo + x residual + LN1 partials ----
  f32x4 oa[2][4];
#pragma unroll
  for (int m = 0; m < 2; ++m)
#pragma unroll
    for (int n = 0; n < 4; ++n) oa[m][n] = (f32x4){0.f, 0.f, 0.f, 0.f};
  gemmT<2, 4>(Cbuf, WoT, 256, cw, 0, li, hi, oa);
  {
#pragma unroll
    for (int n = 0; n < 4; ++n) {
      float bon = bo[cw + 16 * n + li];
#pragma unroll
      for (int m = 0; m < 2; ++m)
#pragma unroll
        for (int j = 0; j < 4; ++j) {
          int r = 16 * m + 4 * hi + j;
          oa[m][n][j] += bon + xt[r * 256 + cw + 16 * n + li];
        }
    }
#pragma unroll
    for (int m = 0; m < 2; ++m)
#pragma unroll
      for (int j = 0; j < 4; ++j) {
        int r = 16 * m + 4 * hi + j;
        float sv = oa[m][0][j] + oa[m][1][j] + oa[m][2][j] + oa[m][3][j];
        float qv = oa[m][0][j] * oa[m][0][j] + oa[m][1][j] * oa[m][1][j]
                 + oa[m][2][j] * oa[m][2][j] + oa[m][3][j] * oa[m][3][j];
        float s = red16(sv);
        float q = red16(qv);
        if (li == 0) { scrT[(w * 32 + r) * 2] = s; scrT[(w * 32 + r) * 2 + 1] = q; }
      }
  }
  __syncthreads();
  if (tid < BM) {
    float S = 0.f, Q = 0.f;
#pragma unroll
    for (int ww = 0; ww < 4; ++ww) {
      S += scrT[(ww * 32 + tid) * 2];
      Q += scrT[(ww * 32 + tid) * 2 + 1];
    }
    float mean = S * (1.f / 256.f);
    float var  = Q * (1.f / 256.f) - mean * mean;
    scr2T[tid * 2] = mean;
    scr2T[tid * 2 + 1] = rsqrtf(var + 1e-5f);
  }
  __syncthreads();
  {
#pragma unroll
    for (int n = 0; n < 4; ++n) {
      float g1n = g1[cw + 16 * n + li];
      float b1n = be1[cw + 16 * n + li];
#pragma unroll
      for (int m = 0; m < 2; ++m)
#pragma unroll
        for (int j = 0; j < 4; ++j) {
          int r = 16 * m + 4 * hi + j;
          float mean = scr2T[r * 2], rs = scr2T[r * 2 + 1];
          *(short*)(Cbuf + swz(r, cw + 16 * n + li)) =
              f2bf((oa[m][n][j] - mean) * rs * g1n + b1n);
        }
    }
  }
  __syncthreads();

  // ---- coalesced bf16 h store ----
  {
    short* hrow = hout + row0 * 256;
#pragma unroll
    for (int t = 0; t < 4; ++t) {
      int idx = t * THREADS + tid;      // 0..1023 16B slots
      int r = idx >> 5, c16 = idx & 31;
      bf16x8 v = *(bf16x8*)(Cbuf + r * 512 + ((c16 * 16) ^ ((r & 7) << 4)));
      *(bf16x8*)(hrow + r * 256 + c16 * 8) = v;
    }
  }
}

// ================= kernel B: FFN + residual + LN2 -> out (f32) =================
__global__ __launch_bounds__(THREADS, 4)
void ffn_ln2(const short* __restrict__ hin, const float* __restrict__ b1,
             const float* __restrict__ b2,
             const float* __restrict__ g2, const float* __restrict__ be2,
             const short* __restrict__ wt, float* __restrict__ out) {
  extern __shared__ char sm[];
  char* Cbuf = sm;              // h tile -> LN2 scratch
  char* Tbuf = sm + 16384;      // hid chunk -> out stage
  float* scrC  = (float*)Cbuf;
  float* scr2C = (float*)(Cbuf + 2048);

  const short* W1T = wt + 262144;
  const short* W2T = wt + 524288;

  const int tid  = threadIdx.x;
  const int w    = tid >> 6;
  const int lane = tid & 63;
  const int li   = lane & 15;
  const int hi   = lane >> 4;
  const int cw   = w * 64;
  const size_t row0 = (size_t)blockIdx.x * BM;

  // ---- stage h (bf16) -> Cbuf swizzled ----
  {
    const short* hrow = hin + row0 * 256;
#pragma unroll
    for (int t = 0; t < 4; ++t) {
      int idx = t * THREADS + tid;      // 0..1023 16B slots
      int r = idx >> 5, c16 = idx & 31;
      bf16x8 v = *(const bf16x8*)(hrow + r * 256 + c16 * 8);
      *(bf16x8*)(Cbuf + r * 512 + ((c16 * 16) ^ ((r & 7) << 4))) = v;
    }
  }
  __syncthreads();

  // ---- FFN: 4 chunks of 256 hidden ----
  f32x4 a2[2][4];
#pragma unroll
  for (int m = 0; m < 2; ++m)
#pragma unroll
    for (int n = 0; n < 4; ++n) a2[m][n] = (f32x4){0.f, 0.f, 0.f, 0.f};
#pragma unroll 1
  for (int c = 0; c < 4; ++c) {
#pragma unroll
    for (int g = 0; g < 2; ++g) {
      f32x4 a1[2][2];
#pragma unroll
      for (int m = 0; m < 2; ++m)
#pragma unroll
        for (int n = 0; n < 2; ++n) a1[m][n] = (f32x4){0.f, 0.f, 0.f, 0.f};
      gemmT<2, 2>(Cbuf, W1T, 256, 256 * c + cw + 32 * g, 0, li, hi, a1);
#pragma unroll
      for (int n = 0; n < 2; ++n) {
        float b1n = b1[256 * c + cw + 32 * g + 16 * n + li];
#pragma unroll
        for (int m = 0; m < 2; ++m)
#pragma unroll
          for (int j = 0; j < 4; ++j) {
            int r = 16 * m + 4 * hi + j;
            *(short*)(Tbuf + swz(r, cw + 32 * g + 16 * n + li)) =
                f2bf(fmaxf(a1[m][n][j] + b1n, 0.f));
          }
      }
    }
    __syncthreads();
    gemmT<2, 4>(Tbuf, W2T, 1024, cw, 256 * c, li, hi, a2);
    __syncthreads();
  }

  // ---- +b2 + h residual; LN2 partials ----
  {
#pragma unroll
    for (int n = 0; n < 4; ++n) {
      float b2n = b2[cw + 16 * n + li];
#pragma unroll
      for (int m = 0; m < 2; ++m)
#pragma unroll
        for (int j = 0; j < 4; ++j) {
          int r = 16 * m + 4 * hi + j;
          a2[m][n][j] += b2n + bf2f(*(short*)(Cbuf + swz(r, cw + 16 * n + li)));
        }
    }
  }
  __syncthreads();   // all h reads done before scrC overwrites Cbuf
#pragma unroll
  for (int m = 0; m < 2; ++m)
#pragma unroll
    for (int j = 0; j < 4; ++j) {
      int r = 16 * m + 4 * hi + j;
      float sv = a2[m][0][j] + a2[m][1][j] + a2[m][2][j] + a2[m][3][j];
      float qv = a2[m][0][j] * a2[m][0][j] + a2[m][1][j] * a2[m][1][j]
               + a2[m][2][j] * a2[m][2][j] + a2[m][3][j] * a2[m][3][j];
      float s = red16(sv);
      float q = red16(qv);
      if (li == 0) { scrC[(w * 32 + r) * 2] = s; scrC[(w * 32 + r) * 2 + 1] = q; }
    }
  __syncthreads();
  if (tid < BM) {
    float S = 0.f, Q = 0.f;
#pragma unroll
    for (int ww = 0; ww < 4; ++ww) {
      S += scrC[(ww * 32 + tid) * 2];
      Q += scrC[(ww * 32 + tid) * 2 + 1];
    }
    float mean = S * (1.f / 256.f);
    float var  = Q * (1.f / 256.f) - mean * mean;
    scr2C[tid * 2] = mean;
    scr2C[tid * 2 + 1] = rsqrtf(var + 1e-5f);
  }
  __syncthreads();

  // ---- LN2 apply + coalesced store via Tbuf f32 stage (2 halves of 16 rows) ----
  {
    float g2n[4], b2n[4];
#pragma unroll
    for (int n = 0; n < 4; ++n) {
      g2n[n] = g2[cw + 16 * n + li];
      b2n[n] = be2[cw + 16 * n + li];
    }
    float* orow = out + row0 * 256;
#pragma unroll
    for (int hf = 0; hf < 2; ++hf) {           // hf == m
#pragma unroll
      for (int n = 0; n < 4; ++n)
#pragma unroll
        for (int j = 0; j < 4; ++j) {
          int r = 16 * hf + 4 * hi + j;
          float mean = scr2C[r * 2], rs = scr2C[r * 2 + 1];
          int rr = 4 * hi + j;
          *(float*)(Tbuf + rr * 1024 + (((cw + 16 * n + li) * 4) ^ ((rr & 7) << 4)))
              = (a2[hf][n][j] - mean) * rs * g2n[n] + b2n[n];
        }
      __syncthreads();
#pragma unroll
      for (int t = 0; t < 4; ++t) {
        int idx = t * THREADS + tid;           // 0..1023 float4 slots
        int r = idx >> 6, c4 = idx & 63;       // r 0..15
        f32x4 v = *(f32x4*)(Tbuf + r * 1024 + ((c4 * 16) ^ ((r & 7) << 4)));
        *(f32x4*)(orow + (hf * 16 + r) * 256 + c4 * 4) = v;
      }
      __syncthreads();
    }
  }
}

extern "C" void kernel_launch(void* const* d_in, const int* in_sizes, int n_in,
                              void* d_out, int out_size, void* d_ws, size_t ws_size,
                              hipStream_t stream) {
  const float* x   = (const float*)d_in[0];
  const float* sx  = (const float*)d_in[1];
  const float* dx  = (const float*)d_in[2];
  const float* Wq  = (const float*)d_in[3];
  const float* bq  = (const float*)d_in[4];
  const float* Wk  = (const float*)d_in[5];
  const float* Wv  = (const float*)d_in[7];
  const float* bv  = (const float*)d_in[8];
  const float* Wo  = (const float*)d_in[9];
  const float* bo  = (const float*)d_in[10];
  const float* W1  = (const float*)d_in[11];
  const float* b1  = (const float*)d_in[12];
  const float* W2  = (const float*)d_in[13];
  const float* b2  = (const float*)d_in[14];
  const float* g1  = (const float*)d_in[15];
  const float* be1 = (const float*)d_in[16];
  const float* g2  = (const float*)d_in[17];
  const float* be2 = (const float*)d_in[18];
  short* wt = (short*)d_ws;
  short* hbuf = wt + 786432;

  prep<<<dim3(1536), dim3(512), 0, stream>>>(Wq, Wk, Wv, Wo, W1, W2, wt);
  attn_ln1<<<dim3(NROWS / BM), dim3(THREADS), LDSB_A, stream>>>(
      x, sx, dx, bq, bv, bo, g1, be1, wt, hbuf);
  ffn_ln2<<<dim3(NROWS / BM), dim3(THREADS), LDSB_B, stream>>>(
      hbuf, b1, b2, g2, be2, wt, (float*)d_out);
}

// Round 9
// 1168.672 us; speedup vs baseline: 1.4834x; 1.4834x over previous
//
#include <hip/hip_runtime.h>
#include <hip/hip_bf16.h>
#include <math.h>

#define NROWS   262144
#define BM      64
#define THREADS 256
#define LDSB_A  (65536 + 2048)
#define LDSB_B  65536

using bf16x8 = __attribute__((ext_vector_type(8))) short;
using s16x4  = __attribute__((ext_vector_type(4))) short;
using f32x4  = __attribute__((ext_vector_type(4))) float;

__device__ __forceinline__ short f2bf(float f) {
  __hip_bfloat16 h = __float2bfloat16(f);
  return __builtin_bit_cast(short, h);
}
__device__ __forceinline__ float bf2f(short s) {
  __hip_bfloat16 h = __builtin_bit_cast(__hip_bfloat16, s);
  return __bfloat162float(h);
}
// XOR-swizzled byte offset into a [64][256] bf16 LDS tile (row stride 512B)
__device__ __forceinline__ int swz(int row, int col) {
  return row * 512 + ((col * 2) ^ ((row & 7) << 4));
}

__device__ __forceinline__ float red16(float p) {
  p += __shfl_xor(p, 1, 64);
  p += __shfl_xor(p, 2, 64);
  p += __shfl_xor(p, 4, 64);
  p += __shfl_xor(p, 8, 64);
  return p;
}

// stage a [64][256] f32 global tile -> swizzled bf16 LDS tile (256 threads)
__device__ __forceinline__ void stage_tile(char* __restrict__ buf,
                                           const float* __restrict__ g, int tid) {
#pragma unroll 2
  for (int it = 0; it < 16; ++it) {
    int idx = it * THREADS + tid;          // 0..4095 float4 slots
    int r = idx >> 6;                       // 0..63
    int c = (idx & 63) << 2;
    float4 v = *(const float4*)(g + r * 256 + c);
    s16x4 o;
    o[0] = f2bf(v.x); o[1] = f2bf(v.y); o[2] = f2bf(v.z); o[3] = f2bf(v.w);
    *(s16x4*)(buf + swz(r, c)) = o;
  }
}

// C[64 rows x NF*16 cols] += A_lds[64 x 256] @ WT[cols][Kw] (B pre-transposed bf16)
template <int MF, int NF>
__device__ __forceinline__ void gemmT(const char* __restrict__ Abuf,
                                      const short* __restrict__ WT, int Kw,
                                      int col0, int koff, int li, int hi,
                                      f32x4 (&acc)[MF][NF]) {
  const short* wp[NF];
#pragma unroll
  for (int n = 0; n < NF; ++n)
    wp[n] = WT + (size_t)(col0 + 16 * n + li) * Kw + koff + hi * 8;
#pragma unroll 2
  for (int kk = 0; kk < 256; kk += 32) {
    int ka = kk + hi * 8;
    bf16x8 b[NF];
#pragma unroll
    for (int n = 0; n < NF; ++n) b[n] = *(const bf16x8*)(wp[n] + kk);
    bf16x8 a[MF];
#pragma unroll
    for (int m = 0; m < MF; ++m)
      a[m] = *(const bf16x8*)(Abuf + swz(16 * m + li, ka));
#pragma unroll
    for (int m = 0; m < MF; ++m)
#pragma unroll
      for (int n = 0; n < NF; ++n)
        acc[m][n] = __builtin_amdgcn_mfma_f32_16x16x32_bf16(a[m], b[n], acc[m][n], 0, 0, 0);
  }
}

// transpose + bf16-convert all weights (Wq pre-scaled by 1/sqrt(DH)):
// WqT,WkT,WvT,WoT: [256][256]; W1T: [1024][256]; W2T: [256][1024]
__global__ void prep(const float* __restrict__ Wq, const float* __restrict__ Wk,
                     const float* __restrict__ Wv, const float* __restrict__ Wo,
                     const float* __restrict__ W1, const float* __restrict__ W2,
                     short* __restrict__ wt) {
  int idx = blockIdx.x * blockDim.x + threadIdx.x;  // 0..786431
  if (idx < 262144) {
    int m = idx >> 16;
    const float* W = (m == 0) ? Wq : (m == 1) ? Wk : (m == 2) ? Wv : Wo;
    float s = (m == 0) ? 0.17677669529663687f : 1.0f;
    int l = idx & 65535;
    int n = l >> 8, k = l & 255;
    wt[idx] = f2bf(W[k * 256 + n] * s);
  } else if (idx < 524288) {
    int l = idx - 262144;
    int n = l >> 8, k = l & 255;
    wt[idx] = f2bf(W1[k * 1024 + n]);
  } else {
    int l = idx - 524288;
    int n = l >> 10, k = l & 1023;
    wt[idx] = f2bf(W2[k * 256 + n]);
  }
}

// ================= kernel A: attention + O-proj + LN1 -> h (bf16) =================
__global__ __launch_bounds__(THREADS, 2)
void attn_ln1(const float* __restrict__ x, const float* __restrict__ sx,
              const float* __restrict__ dx,
              const float* __restrict__ bq, const float* __restrict__ bv,
              const float* __restrict__ bo,
              const float* __restrict__ g1, const float* __restrict__ be1,
              const short* __restrict__ wt, short* __restrict__ hout) {
  extern __shared__ char sm[];
  char* Tbuf = sm;              // x tile -> src tile -> LN1 scratch
  char* Cbuf = sm + 32768;      // dst tile -> ctx -> h stage
  float* sc    = (float*)(sm + 65536);   // [4 waves][2 heads][64 rows] scalars
  float* scrT  = (float*)Tbuf;
  float* scr2T = (float*)(Tbuf + 2048);

  const short* WqT = wt;
  const short* WkT = wt + 65536;
  const short* WvT = wt + 131072;
  const short* WoT = wt + 196608;

  const int tid  = threadIdx.x;
  const int w    = tid >> 6;              // 0..3
  const int lane = tid & 63;
  const int li   = lane & 15;
  const int hi   = lane >> 4;
  const int cw   = w * 64;                // wave col slice (2 heads)
  const size_t row0 = (size_t)blockIdx.x * BM;

  const float* xt = x  + row0 * 256;
  const float* st = sx + row0 * 256;
  const float* dt = dx + row0 * 256;

  // ---- P0: stage x ----
  stage_tile(Tbuf, xt, tid);
  __syncthreads();

  // ---- P1: stage dst -> Cbuf; Q gemm (Tbuf, Wq pre-scaled) ----
  f32x4 qa[4][4];
#pragma unroll
  for (int m = 0; m < 4; ++m)
#pragma unroll
    for (int n = 0; n < 4; ++n) qa[m][n] = (f32x4){0.f, 0.f, 0.f, 0.f};
  stage_tile(Cbuf, dt, tid);
  gemmT<4, 4>(Tbuf, WqT, 256, cw, 0, li, hi, qa);
  {
    const float scl = 0.17677669529663687f;
#pragma unroll
    for (int n = 0; n < 4; ++n) {
      float bqn = bq[cw + 16 * n + li] * scl;
#pragma unroll
      for (int m = 0; m < 4; ++m)
#pragma unroll
        for (int j = 0; j < 4; ++j) qa[m][n][j] += bqn;
    }
  }
  __syncthreads();

  // ---- P2: K_dst gemms (per head) -> scores to sc[]; stage src -> Tbuf ----
  {
#pragma unroll
    for (int hh = 0; hh < 2; ++hh) {
      f32x4 ka[4][2];
#pragma unroll
      for (int m = 0; m < 4; ++m)
#pragma unroll
        for (int n = 0; n < 2; ++n) ka[m][n] = (f32x4){0.f, 0.f, 0.f, 0.f};
      gemmT<4, 2>(Cbuf, WkT, 256, cw + 32 * hh, 0, li, hi, ka);
#pragma unroll
      for (int m = 0; m < 4; ++m)
#pragma unroll
        for (int j = 0; j < 4; ++j) {
          float pr = red16(qa[m][2 * hh][j] * ka[m][0][j] +
                           qa[m][2 * hh + 1][j] * ka[m][1][j]);
          if (li == 0) sc[(w * 2 + hh) * 64 + 16 * m + 4 * hi + j] = pr;
        }
    }
    stage_tile(Tbuf, st, tid);
  }
  __syncthreads();

  // ---- P3: K_src gemms -> weights in sc[]; V_src; V_dst; combine ----
#pragma unroll
  for (int hh = 0; hh < 2; ++hh) {
    f32x4 ka[4][2];
#pragma unroll
    for (int m = 0; m < 4; ++m)
#pragma unroll
      for (int n = 0; n < 2; ++n) ka[m][n] = (f32x4){0.f, 0.f, 0.f, 0.f};
    gemmT<4, 2>(Tbuf, WkT, 256, cw + 32 * hh, 0, li, hi, ka);
#pragma unroll
    for (int m = 0; m < 4; ++m)
#pragma unroll
      for (int j = 0; j < 4; ++j) {
        float ps = red16(qa[m][2 * hh][j] * ka[m][0][j] +
                         qa[m][2 * hh + 1][j] * ka[m][1][j]);
        int r = 16 * m + 4 * hi + j;
        float pdv = sc[(w * 2 + hh) * 64 + r];         // lockstep-safe
        float awv = 1.f / (1.f + expf(pdv - ps));       // weight on V_src
        if (li == 0) sc[(w * 2 + hh) * 64 + r] = awv;
      }
  }
  f32x4 vs[4][4];
#pragma unroll
  for (int m = 0; m < 4; ++m)
#pragma unroll
    for (int n = 0; n < 4; ++n) vs[m][n] = (f32x4){0.f, 0.f, 0.f, 0.f};
  gemmT<4, 4>(Tbuf, WvT, 256, cw, 0, li, hi, vs);
#pragma unroll
  for (int hh = 0; hh < 2; ++hh) {
    f32x4 vd[4][2];
#pragma unroll
    for (int m = 0; m < 4; ++m)
#pragma unroll
      for (int n = 0; n < 2; ++n) vd[m][n] = (f32x4){0.f, 0.f, 0.f, 0.f};
    gemmT<4, 2>(Cbuf, WvT, 256, cw + 32 * hh, 0, li, hi, vd);
#pragma unroll
    for (int n = 0; n < 2; ++n) {
      float bvn = bv[cw + 32 * hh + 16 * n + li];
#pragma unroll
      for (int m = 0; m < 4; ++m)
#pragma unroll
        for (int j = 0; j < 4; ++j) {
          float a = sc[(w * 2 + hh) * 64 + 16 * m + 4 * hi + j];
          vs[m][2 * hh + n][j] = a * vs[m][2 * hh + n][j] + (1.f - a) * vd[m][n][j] + bvn;
        }
    }
  }
  __syncthreads();

  // ---- P4: ctx -> Cbuf (bf16, swizzled) ----
#pragma unroll
  for (int m = 0; m < 4; ++m)
#pragma unroll
    for (int n = 0; n < 4; ++n)
#pragma unroll
      for (int j = 0; j < 4; ++j)
        *(short*)(Cbuf + swz(16 * m + 4 * hi + j, cw + 16 * n + li)) = f2bf(vs[m][n][j]);
  __syncthreads();

  // ---- P5: O-proj gemm + bo + x residual + LN1 partials ----
  f32x4 oa[4][4];
#pragma unroll
  for (int m = 0; m < 4; ++m)
#pragma unroll
    for (int n = 0; n < 4; ++n) oa[m][n] = (f32x4){0.f, 0.f, 0.f, 0.f};
  gemmT<4, 4>(Cbuf, WoT, 256, cw, 0, li, hi, oa);
  {
#pragma unroll
    for (int n = 0; n < 4; ++n) {
      float bon = bo[cw + 16 * n + li];
#pragma unroll
      for (int m = 0; m < 4; ++m)
#pragma unroll
        for (int j = 0; j < 4; ++j) {
          int r = 16 * m + 4 * hi + j;
          oa[m][n][j] += bon + xt[r * 256 + cw + 16 * n + li];
        }
    }
#pragma unroll
    for (int m = 0; m < 4; ++m)
#pragma unroll
      for (int j = 0; j < 4; ++j) {
        int r = 16 * m + 4 * hi + j;
        float sv = oa[m][0][j] + oa[m][1][j] + oa[m][2][j] + oa[m][3][j];
        float qv = oa[m][0][j] * oa[m][0][j] + oa[m][1][j] * oa[m][1][j]
                 + oa[m][2][j] * oa[m][2][j] + oa[m][3][j] * oa[m][3][j];
        float s = red16(sv);
        float q = red16(qv);
        if (li == 0) { scrT[(w * 64 + r) * 2] = s; scrT[(w * 64 + r) * 2 + 1] = q; }
      }
  }
  __syncthreads();
  if (tid < BM) {
    float S = 0.f, Q = 0.f;
#pragma unroll
    for (int ww = 0; ww < 4; ++ww) {
      S += scrT[(ww * 64 + tid) * 2];
      Q += scrT[(ww * 64 + tid) * 2 + 1];
    }
    float mean = S * (1.f / 256.f);
    float var  = Q * (1.f / 256.f) - mean * mean;
    scr2T[tid * 2] = mean;
    scr2T[tid * 2 + 1] = rsqrtf(var + 1e-5f);
  }
  __syncthreads();
  {
#pragma unroll
    for (int n = 0; n < 4; ++n) {
      float g1n = g1[cw + 16 * n + li];
      float b1n = be1[cw + 16 * n + li];
#pragma unroll
      for (int m = 0; m < 4; ++m)
#pragma unroll
        for (int j = 0; j < 4; ++j) {
          int r = 16 * m + 4 * hi + j;
          float mean = scr2T[r * 2], rs = scr2T[r * 2 + 1];
          *(short*)(Cbuf + swz(r, cw + 16 * n + li)) =
              f2bf((oa[m][n][j] - mean) * rs * g1n + b1n);
        }
    }
  }
  __syncthreads();

  // ---- coalesced bf16 h store ----
  {
    short* hrow = hout + row0 * 256;
#pragma unroll
    for (int t = 0; t < 8; ++t) {
      int idx = t * THREADS + tid;      // 0..2047 16B slots
      int r = idx >> 5, c16 = idx & 31;
      bf16x8 v = *(bf16x8*)(Cbuf + r * 512 + ((c16 * 16) ^ ((r & 7) << 4)));
      *(bf16x8*)(hrow + r * 256 + c16 * 8) = v;
    }
  }
}

// ================= kernel B: FFN + residual + LN2 -> out (f32) =================
__global__ __launch_bounds__(THREADS, 2)
void ffn_ln2(const short* __restrict__ hin, const float* __restrict__ b1,
             const float* __restrict__ b2,
             const float* __restrict__ g2, const float* __restrict__ be2,
             const short* __restrict__ wt, float* __restrict__ out) {
  extern __shared__ char sm[];
  char* Cbuf = sm;              // h tile -> LN2 scratch
  char* Tbuf = sm + 32768;      // hid chunk -> out stage
  float* scrC  = (float*)Cbuf;
  float* scr2C = (float*)(Cbuf + 2048);

  const short* W1T = wt + 262144;
  const short* W2T = wt + 524288;

  const int tid  = threadIdx.x;
  const int w    = tid >> 6;
  const int lane = tid & 63;
  const int li   = lane & 15;
  const int hi   = lane >> 4;
  const int cw   = w * 64;
  const size_t row0 = (size_t)blockIdx.x * BM;

  // ---- stage h (bf16) -> Cbuf swizzled ----
  {
    const short* hrow = hin + row0 * 256;
#pragma unroll
    for (int t = 0; t < 8; ++t) {
      int idx = t * THREADS + tid;      // 0..2047 16B slots
      int r = idx >> 5, c16 = idx & 31;
      bf16x8 v = *(const bf16x8*)(hrow + r * 256 + c16 * 8);
      *(bf16x8*)(Cbuf + r * 512 + ((c16 * 16) ^ ((r & 7) << 4))) = v;
    }
  }
  __syncthreads();

  // ---- FFN: 4 chunks of 256 hidden ----
  f32x4 a2[4][4];
#pragma unroll
  for (int m = 0; m < 4; ++m)
#pragma unroll
    for (int n = 0; n < 4; ++n) a2[m][n] = (f32x4){0.f, 0.f, 0.f, 0.f};
#pragma unroll 1
  for (int c = 0; c < 4; ++c) {
#pragma unroll
    for (int g = 0; g < 2; ++g) {
      f32x4 a1[4][2];
#pragma unroll
      for (int m = 0; m < 4; ++m)
#pragma unroll
        for (int n = 0; n < 2; ++n) a1[m][n] = (f32x4){0.f, 0.f, 0.f, 0.f};
      gemmT<4, 2>(Cbuf, W1T, 256, 256 * c + cw + 32 * g, 0, li, hi, a1);
#pragma unroll
      for (int n = 0; n < 2; ++n) {
        float b1n = b1[256 * c + cw + 32 * g + 16 * n + li];
#pragma unroll
        for (int m = 0; m < 4; ++m)
#pragma unroll
          for (int j = 0; j < 4; ++j) {
            int r = 16 * m + 4 * hi + j;
            *(short*)(Tbuf + swz(r, cw + 32 * g + 16 * n + li)) =
                f2bf(fmaxf(a1[m][n][j] + b1n, 0.f));
          }
      }
    }
    __syncthreads();
    gemmT<4, 4>(Tbuf, W2T, 1024, cw, 256 * c, li, hi, a2);
    __syncthreads();
  }

  // ---- +b2 + h residual ----
  {
#pragma unroll
    for (int n = 0; n < 4; ++n) {
      float b2n = b2[cw + 16 * n + li];
#pragma unroll
      for (int m = 0; m < 4; ++m)
#pragma unroll
        for (int j = 0; j < 4; ++j) {
          int r = 16 * m + 4 * hi + j;
          a2[m][n][j] += b2n + bf2f(*(short*)(Cbuf + swz(r, cw + 16 * n + li)));
        }
    }
  }
  __syncthreads();   // all h reads done before scrC overwrites Cbuf

  // ---- LN2 partials ----
#pragma unroll
  for (int m = 0; m < 4; ++m)
#pragma unroll
    for (int j = 0; j < 4; ++j) {
      int r = 16 * m + 4 * hi + j;
      float sv = a2[m][0][j] + a2[m][1][j] + a2[m][2][j] + a2[m][3][j];
      float qv = a2[m][0][j] * a2[m][0][j] + a2[m][1][j] * a2[m][1][j]
               + a2[m][2][j] * a2[m][2][j] + a2[m][3][j] * a2[m][3][j];
      float s = red16(sv);
      float q = red16(qv);
      if (li == 0) { scrC[(w * 64 + r) * 2] = s; scrC[(w * 64 + r) * 2 + 1] = q; }
    }
  __syncthreads();
  if (tid < BM) {
    float S = 0.f, Q = 0.f;
#pragma unroll
    for (int ww = 0; ww < 4; ++ww) {
      S += scrC[(ww * 64 + tid) * 2];
      Q += scrC[(ww * 64 + tid) * 2 + 1];
    }
    float mean = S * (1.f / 256.f);
    float var  = Q * (1.f / 256.f) - mean * mean;
    scr2C[tid * 2] = mean;
    scr2C[tid * 2 + 1] = rsqrtf(var + 1e-5f);
  }
  __syncthreads();

  // ---- LN2 apply + coalesced store via Tbuf f32 stage (2 halves of 32 rows) ----
  {
    float g2n[4], b2n[4];
#pragma unroll
    for (int n = 0; n < 4; ++n) {
      g2n[n] = g2[cw + 16 * n + li];
      b2n[n] = be2[cw + 16 * n + li];
    }
    float* orow = out + row0 * 256;
#pragma unroll
    for (int hf = 0; hf < 2; ++hf) {
#pragma unroll
      for (int m2 = 0; m2 < 2; ++m2) {
        int m = 2 * hf + m2;
#pragma unroll
        for (int n = 0; n < 4; ++n)
#pragma unroll
          for (int j = 0; j < 4; ++j) {
            int r = 16 * m + 4 * hi + j;
            float mean = scr2C[r * 2], rs = scr2C[r * 2 + 1];
            int rr = r - 32 * hf;
            *(float*)(Tbuf + rr * 1024 + (((cw + 16 * n + li) * 4) ^ ((rr & 7) << 4)))
                = (a2[m][n][j] - mean) * rs * g2n[n] + b2n[n];
          }
      }
      __syncthreads();
#pragma unroll
      for (int t = 0; t < 8; ++t) {
        int idx = t * THREADS + tid;           // 0..2047 float4 slots
        int r = idx >> 6, c4 = idx & 63;       // r 0..31
        f32x4 v = *(f32x4*)(Tbuf + r * 1024 + ((c4 * 16) ^ ((r & 7) << 4)));
        *(f32x4*)(orow + (hf * 32 + r) * 256 + c4 * 4) = v;
      }
      __syncthreads();
    }
  }
}

extern "C" void kernel_launch(void* const* d_in, const int* in_sizes, int n_in,
                              void* d_out, int out_size, void* d_ws, size_t ws_size,
                              hipStream_t stream) {
  const float* x   = (const float*)d_in[0];
  const float* sx  = (const float*)d_in[1];
  const float* dx  = (const float*)d_in[2];
  const float* Wq  = (const float*)d_in[3];
  const float* bq  = (const float*)d_in[4];
  const float* Wk  = (const float*)d_in[5];
  const float* Wv  = (const float*)d_in[7];
  const float* bv  = (const float*)d_in[8];
  const float* Wo  = (const float*)d_in[9];
  const float* bo  = (const float*)d_in[10];
  const float* W1  = (const float*)d_in[11];
  const float* b1  = (const float*)d_in[12];
  const float* W2  = (const float*)d_in[13];
  const float* b2  = (const float*)d_in[14];
  const float* g1  = (const float*)d_in[15];
  const float* be1 = (const float*)d_in[16];
  const float* g2  = (const float*)d_in[17];
  const float* be2 = (const float*)d_in[18];
  short* wt = (short*)d_ws;
  short* hbuf = wt + 786432;

  prep<<<dim3(1536), dim3(512), 0, stream>>>(Wq, Wk, Wv, Wo, W1, W2, wt);
  attn_ln1<<<dim3(NROWS / BM), dim3(THREADS), LDSB_A, stream>>>(
      x, sx, dx, bq, bv, bo, g1, be1, wt, hbuf);
  ffn_ln2<<<dim3(NROWS / BM), dim3(THREADS), LDSB_B, stream>>>(
      hbuf, b1, b2, g2, be2, wt, (float*)d_out);
}

// Round 10
// 1130.262 us; speedup vs baseline: 1.5338x; 1.0340x over previous
//
#include <hip/hip_runtime.h>
#include <hip/hip_bf16.h>
#include <math.h>

#define NROWS   262144
#define BM      64
#define THREADS 256
#define LDSB_A  (32768 + 32768 + 2048 + 1024)
#define LDSB_B  65536

using bf16x8 = __attribute__((ext_vector_type(8))) short;
using s16x4  = __attribute__((ext_vector_type(4))) short;
using f32x4  = __attribute__((ext_vector_type(4))) float;

__device__ __forceinline__ short f2bf(float f) {
  __hip_bfloat16 h = __float2bfloat16(f);
  return __builtin_bit_cast(short, h);
}
__device__ __forceinline__ float bf2f(short s) {
  __hip_bfloat16 h = __builtin_bit_cast(__hip_bfloat16, s);
  return __bfloat162float(h);
}
__device__ __forceinline__ unsigned pack2(float a, float b) {
  return (unsigned)(unsigned short)f2bf(a) | ((unsigned)(unsigned short)f2bf(b) << 16);
}
// XOR-swizzled byte offset into a [64][256] bf16 LDS tile (row stride 512B)
__device__ __forceinline__ int swz(int row, int col) {
  return row * 512 + ((col * 2) ^ ((row & 7) << 4));
}

__device__ __forceinline__ float red16(float p) {
  p += __shfl_xor(p, 1, 64);
  p += __shfl_xor(p, 2, 64);
  p += __shfl_xor(p, 4, 64);
  p += __shfl_xor(p, 8, 64);
  return p;
}

// C[64 rows x NF*16 cols] += A_lds[64 x 256] @ WT[cols][Kw] (B pre-transposed bf16)
template <int MF, int NF>
__device__ __forceinline__ void gemmT(const char* __restrict__ Abuf,
                                      const short* __restrict__ WT, int Kw,
                                      int col0, int koff, int li, int hi,
                                      f32x4 (&acc)[MF][NF]) {
  const short* wp[NF];
#pragma unroll
  for (int n = 0; n < NF; ++n)
    wp[n] = WT + (size_t)(col0 + 16 * n + li) * Kw + koff + hi * 8;
#pragma unroll 2
  for (int kk = 0; kk < 256; kk += 32) {
    int ka = kk + hi * 8;
    bf16x8 b[NF];
#pragma unroll
    for (int n = 0; n < NF; ++n) b[n] = *(const bf16x8*)(wp[n] + kk);
    bf16x8 a[MF];
#pragma unroll
    for (int m = 0; m < MF; ++m)
      a[m] = *(const bf16x8*)(Abuf + swz(16 * m + li, ka));
#pragma unroll
    for (int m = 0; m < MF; ++m)
#pragma unroll
      for (int n = 0; n < NF; ++n)
        acc[m][n] = __builtin_amdgcn_mfma_f32_16x16x32_bf16(a[m], b[n], acc[m][n], 0, 0, 0);
  }
}

// transpose + bf16-convert all weights (Wq pre-scaled by 1/sqrt(DH)):
// WqT,WkT,WvT,WoT: [256][256]; W1T: [1024][256]; W2T: [256][1024]
__global__ void prep(const float* __restrict__ Wq, const float* __restrict__ Wk,
                     const float* __restrict__ Wv, const float* __restrict__ Wo,
                     const float* __restrict__ W1, const float* __restrict__ W2,
                     short* __restrict__ wt) {
  int idx = blockIdx.x * blockDim.x + threadIdx.x;  // 0..786431
  if (idx < 262144) {
    int m = idx >> 16;
    const float* W = (m == 0) ? Wq : (m == 1) ? Wk : (m == 2) ? Wv : Wo;
    float s = (m == 0) ? 0.17677669529663687f : 1.0f;
    int l = idx & 65535;
    int n = l >> 8, k = l & 255;
    wt[idx] = f2bf(W[k * 256 + n] * s);
  } else if (idx < 524288) {
    int l = idx - 262144;
    int n = l >> 8, k = l & 255;
    wt[idx] = f2bf(W1[k * 1024 + n]);
  } else {
    int l = idx - 524288;
    int n = l >> 10, k = l & 1023;
    wt[idx] = f2bf(W2[k * 256 + n]);
  }
}

// ================= kernel A: attention + O-proj + LN1 -> h (bf16) =================
__global__ __launch_bounds__(THREADS, 2)
void attn_ln1(const float* __restrict__ x, const float* __restrict__ sx,
              const float* __restrict__ dx,
              const float* __restrict__ bq, const float* __restrict__ bv,
              const float* __restrict__ bo,
              const float* __restrict__ g1, const float* __restrict__ be1,
              const short* __restrict__ wt, short* __restrict__ hout) {
  extern __shared__ char sm[];
  char* Cbuf = sm;              // x tile (persistent) -> h
  char* Tbuf = sm + 32768;      // dst -> src -> ctx
  float* sc    = (float*)(sm + 65536);          // [4 waves][2 heads][64 rows]
  float* scrL  = (float*)(sm + 65536 + 2048);   // LN1 partials (512B)
  float* scr2L = (float*)(sm + 65536 + 2560);   // LN1 mean/rstd (512B)

  const short* WqT = wt;
  const short* WkT = wt + 65536;
  const short* WvT = wt + 131072;
  const short* WoT = wt + 196608;

  const int tid  = threadIdx.x;
  const int w    = tid >> 6;              // 0..3
  const int lane = tid & 63;
  const int li   = lane & 15;
  const int hi   = lane >> 4;
  const int cw   = w * 64;                // wave col slice (2 heads)
  const size_t row0 = (size_t)blockIdx.x * BM;

  const float* xt = x  + row0 * 256;
  const float* st = sx + row0 * 256;
  const float* dt = dx + row0 * 256;

  float4 ld[16];

  // ---- P0: stage x -> Cbuf (persistent) ----
#pragma unroll
  for (int it = 0; it < 16; ++it) {
    int idx = it * THREADS + tid;
    ld[it] = *(const float4*)(xt + (idx >> 6) * 256 + ((idx & 63) << 2));
  }
#pragma unroll
  for (int it = 0; it < 16; ++it) {
    int idx = it * THREADS + tid;
    int r = idx >> 6, c = (idx & 63) << 2;
    s16x4 o;
    o[0] = f2bf(ld[it].x); o[1] = f2bf(ld[it].y);
    o[2] = f2bf(ld[it].z); o[3] = f2bf(ld[it].w);
    *(s16x4*)(Cbuf + swz(r, c)) = o;
  }
  __syncthreads();

  // ---- P1: issue dst loads; Q gemm (Cbuf); pack q->bf16; write dst->Tbuf ----
#pragma unroll
  for (int it = 0; it < 16; ++it) {
    int idx = it * THREADS + tid;
    ld[it] = *(const float4*)(dt + (idx >> 6) * 256 + ((idx & 63) << 2));
  }
  unsigned qb[4][4][2];
  {
    f32x4 qa[4][4];
#pragma unroll
    for (int m = 0; m < 4; ++m)
#pragma unroll
      for (int n = 0; n < 4; ++n) qa[m][n] = (f32x4){0.f, 0.f, 0.f, 0.f};
    gemmT<4, 4>(Cbuf, WqT, 256, cw, 0, li, hi, qa);
    const float scl = 0.17677669529663687f;
#pragma unroll
    for (int n = 0; n < 4; ++n) {
      float bqn = bq[cw + 16 * n + li] * scl;
#pragma unroll
      for (int m = 0; m < 4; ++m) {
        qb[m][n][0] = pack2(qa[m][n][0] + bqn, qa[m][n][1] + bqn);
        qb[m][n][1] = pack2(qa[m][n][2] + bqn, qa[m][n][3] + bqn);
      }
    }
  }
#pragma unroll
  for (int it = 0; it < 16; ++it) {
    int idx = it * THREADS + tid;
    int r = idx >> 6, c = (idx & 63) << 2;
    s16x4 o;
    o[0] = f2bf(ld[it].x); o[1] = f2bf(ld[it].y);
    o[2] = f2bf(ld[it].z); o[3] = f2bf(ld[it].w);
    *(s16x4*)(Tbuf + swz(r, c)) = o;
  }
  __syncthreads();

  // helper macro: unpack packed q (all indices compile-time in unrolled loops)
#define QF(m, n, j) bf2f((short)(((j) & 1) ? (qb[m][n][(j) >> 1] >> 16) \
                                           : (qb[m][n][(j) >> 1] & 0xffffu)))

  // ---- P2: issue src loads; K_dst scores; V_dst (held in regs) ----
#pragma unroll
  for (int it = 0; it < 16; ++it) {
    int idx = it * THREADS + tid;
    ld[it] = *(const float4*)(st + (idx >> 6) * 256 + ((idx & 63) << 2));
  }
#pragma unroll
  for (int hh = 0; hh < 2; ++hh) {
    f32x4 ka[4][2];
#pragma unroll
    for (int m = 0; m < 4; ++m)
#pragma unroll
      for (int n = 0; n < 2; ++n) ka[m][n] = (f32x4){0.f, 0.f, 0.f, 0.f};
    gemmT<4, 2>(Tbuf, WkT, 256, cw + 32 * hh, 0, li, hi, ka);
#pragma unroll
    for (int m = 0; m < 4; ++m)
#pragma unroll
      for (int j = 0; j < 4; ++j) {
        float pr = red16(QF(m, 2 * hh, j) * ka[m][0][j] +
                         QF(m, 2 * hh + 1, j) * ka[m][1][j]);
        if (li == 0) sc[(w * 2 + hh) * 64 + 16 * m + 4 * hi + j] = pr;
      }
  }
  f32x4 vd[4][4];
#pragma unroll
  for (int m = 0; m < 4; ++m)
#pragma unroll
    for (int n = 0; n < 4; ++n) vd[m][n] = (f32x4){0.f, 0.f, 0.f, 0.f};
  gemmT<4, 4>(Tbuf, WvT, 256, cw, 0, li, hi, vd);
  __syncthreads();                 // all waves done reading dst
#pragma unroll
  for (int it = 0; it < 16; ++it) {
    int idx = it * THREADS + tid;
    int r = idx >> 6, c = (idx & 63) << 2;
    s16x4 o;
    o[0] = f2bf(ld[it].x); o[1] = f2bf(ld[it].y);
    o[2] = f2bf(ld[it].z); o[3] = f2bf(ld[it].w);
    *(s16x4*)(Tbuf + swz(r, c)) = o;
  }
  __syncthreads();

  // ---- P3: K_src scores -> weights; V_src; combine; ctx -> Tbuf ----
#pragma unroll
  for (int hh = 0; hh < 2; ++hh) {
    f32x4 ka[4][2];
#pragma unroll
    for (int m = 0; m < 4; ++m)
#pragma unroll
      for (int n = 0; n < 2; ++n) ka[m][n] = (f32x4){0.f, 0.f, 0.f, 0.f};
    gemmT<4, 2>(Tbuf, WkT, 256, cw + 32 * hh, 0, li, hi, ka);
#pragma unroll
    for (int m = 0; m < 4; ++m)
#pragma unroll
      for (int j = 0; j < 4; ++j) {
        float ps = red16(QF(m, 2 * hh, j) * ka[m][0][j] +
                         QF(m, 2 * hh + 1, j) * ka[m][1][j]);
        int r = 16 * m + 4 * hi + j;
        float pdv = sc[(w * 2 + hh) * 64 + r];        // lockstep-safe
        float awv = 1.f / (1.f + expf(pdv - ps));      // weight on V_src
        if (li == 0) sc[(w * 2 + hh) * 64 + r] = awv;
      }
  }
  {
    f32x4 vs[4][4];
#pragma unroll
    for (int m = 0; m < 4; ++m)
#pragma unroll
      for (int n = 0; n < 4; ++n) vs[m][n] = (f32x4){0.f, 0.f, 0.f, 0.f};
    gemmT<4, 4>(Tbuf, WvT, 256, cw, 0, li, hi, vs);
#pragma unroll
    for (int hh = 0; hh < 2; ++hh)
#pragma unroll
      for (int n2 = 0; n2 < 2; ++n2) {
        int n = 2 * hh + n2;
        float bvn = bv[cw + 16 * n + li];
#pragma unroll
        for (int m = 0; m < 4; ++m)
#pragma unroll
          for (int j = 0; j < 4; ++j) {
            float a = sc[(w * 2 + hh) * 64 + 16 * m + 4 * hi + j];
            vs[m][n][j] = a * vs[m][n][j] + (1.f - a) * vd[m][n][j] + bvn;
          }
      }
    __syncthreads();               // all waves done reading src
#pragma unroll
    for (int m = 0; m < 4; ++m)
#pragma unroll
      for (int n = 0; n < 4; ++n)
#pragma unroll
        for (int j = 0; j < 4; ++j)
          *(short*)(Tbuf + swz(16 * m + 4 * hi + j, cw + 16 * n + li)) = f2bf(vs[m][n][j]);
  }
  __syncthreads();

  // ---- P4: O-proj gemm + bo + x residual (from Cbuf) + LN1 -> h -> Cbuf ----
  f32x4 oa[4][4];
#pragma unroll
  for (int m = 0; m < 4; ++m)
#pragma unroll
    for (int n = 0; n < 4; ++n) oa[m][n] = (f32x4){0.f, 0.f, 0.f, 0.f};
  gemmT<4, 4>(Tbuf, WoT, 256, cw, 0, li, hi, oa);
  {
#pragma unroll
    for (int n = 0; n < 4; ++n) {
      float bon = bo[cw + 16 * n + li];
#pragma unroll
      for (int m = 0; m < 4; ++m)
#pragma unroll
        for (int j = 0; j < 4; ++j) {
          int r = 16 * m + 4 * hi + j;
          float xv = bf2f(*(short*)(Cbuf + swz(r, cw + 16 * n + li)));
          oa[m][n][j] += bon + xv;
        }
    }
#pragma unroll
    for (int m = 0; m < 4; ++m)
#pragma unroll
      for (int j = 0; j < 4; ++j) {
        int r = 16 * m + 4 * hi + j;
        float sv = oa[m][0][j] + oa[m][1][j] + oa[m][2][j] + oa[m][3][j];
        float qv = oa[m][0][j] * oa[m][0][j] + oa[m][1][j] * oa[m][1][j]
                 + oa[m][2][j] * oa[m][2][j] + oa[m][3][j] * oa[m][3][j];
        float s = red16(sv);
        float q = red16(qv);
        if (li == 0) { scrL[(w * 64 + r) & 63 ? 0 : 0] = 0.f; }  // (placeholder avoided below)
        if (li == 0) { scrL[r * 2 - r * 2] = scrL[0]; }
      }
  }
  // NOTE: partials must be per-row accumulated across the 4 waves; use atomic-free
  // two-step: each wave writes its own slice then tid<64 reduces.
  // (rewritten without the placeholder above)
  __syncthreads();
  // -- recompute partial write cleanly --
  {
#pragma unroll
    for (int m = 0; m < 4; ++m)
#pragma unroll
      for (int j = 0; j < 4; ++j) {
        int r = 16 * m + 4 * hi + j;
        float sv = oa[m][0][j] + oa[m][1][j] + oa[m][2][j] + oa[m][3][j];
        float qv = oa[m][0][j] * oa[m][0][j] + oa[m][1][j] * oa[m][1][j]
                 + oa[m][2][j] * oa[m][2][j] + oa[m][3][j] * oa[m][3][j];
        float s = red16(sv);
        float q = red16(qv);
        if (li == 0) { sc[(w * 64 + r) * 2 & 511] = s; }  // reuse sc region (2KB = 512 floats)
        if (li == 0) { sc[((w * 64 + r) * 2 + 1) & 511] = q; }
      }
  }
  __syncthreads();
  if (tid < BM) {
    float S = 0.f, Q = 0.f;
#pragma unroll
    for (int ww = 0; ww < 4; ++ww) {
      S += sc[((ww * 64 + tid) * 2) & 511];
      Q += sc[((ww * 64 + tid) * 2 + 1) & 511];
    }
    float mean = S * (1.f / 256.f);
    float var  = Q * (1.f / 256.f) - mean * mean;
    scr2L[tid * 2] = mean;
    scr2L[tid * 2 + 1] = rsqrtf(var + 1e-5f);
  }
  __syncthreads();
  {
#pragma unroll
    for (int n = 0; n < 4; ++n) {
      float g1n = g1[cw + 16 * n + li];
      float b1n = be1[cw + 16 * n + li];
#pragma unroll
      for (int m = 0; m < 4; ++m)
#pragma unroll
        for (int j = 0; j < 4; ++j) {
          int r = 16 * m + 4 * hi + j;
          float mean = scr2L[r * 2], rs = scr2L[r * 2 + 1];
          *(short*)(Cbuf + swz(r, cw + 16 * n + li)) =
              f2bf((oa[m][n][j] - mean) * rs * g1n + b1n);
        }
    }
  }
  __syncthreads();

  // ---- coalesced bf16 h store ----
  {
    short* hrow = hout + row0 * 256;
#pragma unroll
    for (int t = 0; t < 8; ++t) {
      int idx = t * THREADS + tid;      // 0..2047 16B slots
      int r = idx >> 5, c16 = idx & 31;
      bf16x8 v = *(bf16x8*)(Cbuf + r * 512 + ((c16 * 16) ^ ((r & 7) << 4)));
      *(bf16x8*)(hrow + r * 256 + c16 * 8) = v;
    }
  }
#undef QF
}

// ================= kernel B: FFN + residual + LN2 -> out (f32) =================
__global__ __launch_bounds__(THREADS, 2)
void ffn_ln2(const short* __restrict__ hin, const float* __restrict__ b1,
             const float* __restrict__ b2,
             const float* __restrict__ g2, const float* __restrict__ be2,
             const short* __restrict__ wt, float* __restrict__ out) {
  extern __shared__ char sm[];
  char* Cbuf = sm;              // h tile -> LN2 scratch
  char* Tbuf = sm + 32768;      // hid chunk -> out stage
  float* scrC  = (float*)Cbuf;
  float* scr2C = (float*)(Cbuf + 2048);

  const short* W1T = wt + 262144;
  const short* W2T = wt + 524288;

  const int tid  = threadIdx.x;
  const int w    = tid >> 6;
  const int lane = tid & 63;
  const int li   = lane & 15;
  const int hi   = lane >> 4;
  const int cw   = w * 64;
  const size_t row0 = (size_t)blockIdx.x * BM;

  // ---- stage h (bf16) -> Cbuf swizzled ----
  {
    const short* hrow = hin + row0 * 256;
#pragma unroll
    for (int t = 0; t < 8; ++t) {
      int idx = t * THREADS + tid;      // 0..2047 16B slots
      int r = idx >> 5, c16 = idx & 31;
      bf16x8 v = *(const bf16x8*)(hrow + r * 256 + c16 * 8);
      *(bf16x8*)(Cbuf + r * 512 + ((c16 * 16) ^ ((r & 7) << 4))) = v;
    }
  }
  __syncthreads();

  // ---- FFN: 4 chunks of 256 hidden ----
  f32x4 a2[4][4];
#pragma unroll
  for (int m = 0; m < 4; ++m)
#pragma unroll
    for (int n = 0; n < 4; ++n) a2[m][n] = (f32x4){0.f, 0.f, 0.f, 0.f};
#pragma unroll 1
  for (int c = 0; c < 4; ++c) {
    {
      f32x4 a1[4][4];
#pragma unroll
      for (int m = 0; m < 4; ++m)
#pragma unroll
        for (int n = 0; n < 4; ++n) a1[m][n] = (f32x4){0.f, 0.f, 0.f, 0.f};
      gemmT<4, 4>(Cbuf, W1T, 256, 256 * c + cw, 0, li, hi, a1);
#pragma unroll
      for (int n = 0; n < 4; ++n) {
        float b1n = b1[256 * c + cw + 16 * n + li];
#pragma unroll
        for (int m = 0; m < 4; ++m)
#pragma unroll
          for (int j = 0; j < 4; ++j) {
            int r = 16 * m + 4 * hi + j;
            *(short*)(Tbuf + swz(r, cw + 16 * n + li)) =
                f2bf(fmaxf(a1[m][n][j] + b1n, 0.f));
          }
      }
    }
    __syncthreads();
    gemmT<4, 4>(Tbuf, W2T, 1024, cw, 256 * c, li, hi, a2);
    __syncthreads();
  }

  // ---- +b2 + h residual ----
  {
#pragma unroll
    for (int n = 0; n < 4; ++n) {
      float b2n = b2[cw + 16 * n + li];
#pragma unroll
      for (int m = 0; m < 4; ++m)
#pragma unroll
        for (int j = 0; j < 4; ++j) {
          int r = 16 * m + 4 * hi + j;
          a2[m][n][j] += b2n + bf2f(*(short*)(Cbuf + swz(r, cw + 16 * n + li)));
        }
    }
  }
  __syncthreads();   // all h reads done before scrC overwrites Cbuf

  // ---- LN2 partials ----
#pragma unroll
  for (int m = 0; m < 4; ++m)
#pragma unroll
    for (int j = 0; j < 4; ++j) {
      int r = 16 * m + 4 * hi + j;
      float sv = a2[m][0][j] + a2[m][1][j] + a2[m][2][j] + a2[m][3][j];
      float qv = a2[m][0][j] * a2[m][0][j] + a2[m][1][j] * a2[m][1][j]
               + a2[m][2][j] * a2[m][2][j] + a2[m][3][j] * a2[m][3][j];
      float s = red16(sv);
      float q = red16(qv);
      if (li == 0) { scrC[(w * 64 + r) * 2] = s; scrC[(w * 64 + r) * 2 + 1] = q; }
    }
  __syncthreads();
  if (tid < BM) {
    float S = 0.f, Q = 0.f;
#pragma unroll
    for (int ww = 0; ww < 4; ++ww) {
      S += scrC[(ww * 64 + tid) * 2];
      Q += scrC[(ww * 64 + tid) * 2 + 1];
    }
    float mean = S * (1.f / 256.f);
    float var  = Q * (1.f / 256.f) - mean * mean;
    scr2C[tid * 2] = mean;
    scr2C[tid * 2 + 1] = rsqrtf(var + 1e-5f);
  }
  __syncthreads();

  // ---- LN2 apply + coalesced store via Tbuf f32 stage (2 halves of 32 rows) ----
  {
    float g2n[4], b2n[4];
#pragma unroll
    for (int n = 0; n < 4; ++n) {
      g2n[n] = g2[cw + 16 * n + li];
      b2n[n] = be2[cw + 16 * n + li];
    }
    float* orow = out + row0 * 256;
#pragma unroll
    for (int hf = 0; hf < 2; ++hf) {
#pragma unroll
      for (int m2 = 0; m2 < 2; ++m2) {
        int m = 2 * hf + m2;
#pragma unroll
        for (int n = 0; n < 4; ++n)
#pragma unroll
          for (int j = 0; j < 4; ++j) {
            int r = 16 * m + 4 * hi + j;
            float mean = scr2C[r * 2], rs = scr2C[r * 2 + 1];
            int rr = r - 32 * hf;
            *(float*)(Tbuf + rr * 1024 + (((cw + 16 * n + li) * 4) ^ ((rr & 7) << 4)))
                = (a2[m][n][j] - mean) * rs * g2n[n] + b2n[n];
          }
      }
      __syncthreads();
#pragma unroll
      for (int t = 0; t < 8; ++t) {
        int idx = t * THREADS + tid;           // 0..2047 float4 slots
        int r = idx >> 6, c4 = idx & 63;       // r 0..31
        f32x4 v = *(f32x4*)(Tbuf + r * 1024 + ((c4 * 16) ^ ((r & 7) << 4)));
        *(f32x4*)(orow + (hf * 32 + r) * 256 + c4 * 4) = v;
      }
      __syncthreads();
    }
  }
}

extern "C" void kernel_launch(void* const* d_in, const int* in_sizes, int n_in,
                              void* d_out, int out_size, void* d_ws, size_t ws_size,
                              hipStream_t stream) {
  const float* x   = (const float*)d_in[0];
  const float* sx  = (const float*)d_in[1];
  const float* dx  = (const float*)d_in[2];
  const float* Wq  = (const float*)d_in[3];
  const float* bq  = (const float*)d_in[4];
  const float* Wk  = (const float*)d_in[5];
  const float* Wv  = (const float*)d_in[7];
  const float* bv  = (const float*)d_in[8];
  const float* Wo  = (const float*)d_in[9];
  const float* bo  = (const float*)d_in[10];
  const float* W1  = (const float*)d_in[11];
  const float* b1  = (const float*)d_in[12];
  const float* W2  = (const float*)d_in[13];
  const float* b2  = (const float*)d_in[14];
  const float* g1  = (const float*)d_in[15];
  const float* be1 = (const float*)d_in[16];
  const float* g2  = (const float*)d_in[17];
  const float* be2 = (const float*)d_in[18];
  short* wt = (short*)d_ws;
  short* hbuf = wt + 786432;

  prep<<<dim3(1536), dim3(512), 0, stream>>>(Wq, Wk, Wv, Wo, W1, W2, wt);
  attn_ln1<<<dim3(NROWS / BM), dim3(THREADS), LDSB_A, stream>>>(
      x, sx, dx, bq, bv, bo, g1, be1, wt, hbuf);
  ffn_ln2<<<dim3(NROWS / BM), dim3(THREADS), LDSB_B, stream>>>(
      hbuf, b1, b2, g2, be2, wt, (float*)d_out);
}

// Round 11
// 1083.487 us; speedup vs baseline: 1.6000x; 1.0432x over previous
//
#include <hip/hip_runtime.h>
#include <hip/hip_bf16.h>
#include <math.h>

#define NROWS   262144
#define BM      64
#define THREADS 256
// LDS: Cbuf 32K | Tbuf 32K | sc 2K | scrP 2K | scrM 512B
#define LDSB    (32768 + 32768 + 2048 + 2048 + 512)

using bf16x8 = __attribute__((ext_vector_type(8))) short;
using s16x4  = __attribute__((ext_vector_type(4))) short;
using f32x4  = __attribute__((ext_vector_type(4))) float;

__device__ __forceinline__ short f2bf(float f) {
  __hip_bfloat16 h = __float2bfloat16(f);
  return __builtin_bit_cast(short, h);
}
__device__ __forceinline__ float bf2f(short s) {
  __hip_bfloat16 h = __builtin_bit_cast(__hip_bfloat16, s);
  return __bfloat162float(h);
}
__device__ __forceinline__ unsigned pack2(float a, float b) {
  return (unsigned)(unsigned short)f2bf(a) | ((unsigned)(unsigned short)f2bf(b) << 16);
}
// XOR-swizzled byte offset into a [64][256] bf16 LDS tile (row stride 512B)
__device__ __forceinline__ int swz(int row, int col) {
  return row * 512 + ((col * 2) ^ ((row & 7) << 4));
}

__device__ __forceinline__ float red16(float p) {
  p += __shfl_xor(p, 1, 64);
  p += __shfl_xor(p, 2, 64);
  p += __shfl_xor(p, 4, 64);
  p += __shfl_xor(p, 8, 64);
  return p;
}

// C[64 rows x NF*16 cols] += A_lds[64 x 256] @ WT[cols][Kw] (B pre-transposed bf16)
template <int MF, int NF>
__device__ __forceinline__ void gemmT(const char* __restrict__ Abuf,
                                      const short* __restrict__ WT, int Kw,
                                      int col0, int koff, int li, int hi,
                                      f32x4 (&acc)[MF][NF]) {
  const short* wp[NF];
#pragma unroll
  for (int n = 0; n < NF; ++n)
    wp[n] = WT + (size_t)(col0 + 16 * n + li) * Kw + koff + hi * 8;
#pragma unroll 2
  for (int kk = 0; kk < 256; kk += 32) {
    int ka = kk + hi * 8;
    bf16x8 b[NF];
#pragma unroll
    for (int n = 0; n < NF; ++n) b[n] = *(const bf16x8*)(wp[n] + kk);
    bf16x8 a[MF];
#pragma unroll
    for (int m = 0; m < MF; ++m)
      a[m] = *(const bf16x8*)(Abuf + swz(16 * m + li, ka));
#pragma unroll
    for (int m = 0; m < MF; ++m)
#pragma unroll
      for (int n = 0; n < NF; ++n)
        acc[m][n] = __builtin_amdgcn_mfma_f32_16x16x32_bf16(a[m], b[n], acc[m][n], 0, 0, 0);
  }
}

// transpose + bf16-convert all weights (Wq pre-scaled by 1/sqrt(DH)):
// WqT,WkT,WvT,WoT: [256][256]; W1T: [1024][256]; W2T: [256][1024]
__global__ void prep(const float* __restrict__ Wq, const float* __restrict__ Wk,
                     const float* __restrict__ Wv, const float* __restrict__ Wo,
                     const float* __restrict__ W1, const float* __restrict__ W2,
                     short* __restrict__ wt) {
  int idx = blockIdx.x * blockDim.x + threadIdx.x;  // 0..786431
  if (idx < 262144) {
    int m = idx >> 16;
    const float* W = (m == 0) ? Wq : (m == 1) ? Wk : (m == 2) ? Wv : Wo;
    float s = (m == 0) ? 0.17677669529663687f : 1.0f;
    int l = idx & 65535;
    int n = l >> 8, k = l & 255;
    wt[idx] = f2bf(W[k * 256 + n] * s);
  } else if (idx < 524288) {
    int l = idx - 262144;
    int n = l >> 8, k = l & 255;
    wt[idx] = f2bf(W1[k * 1024 + n]);
  } else {
    int l = idx - 524288;
    int n = l >> 10, k = l & 1023;
    wt[idx] = f2bf(W2[k * 256 + n]);
  }
}

// ================= fused: attention + LN1 + FFN + LN2 =================
__global__ __launch_bounds__(THREADS, 2)
void fused(const float* __restrict__ x, const float* __restrict__ sx,
           const float* __restrict__ dx,
           const float* __restrict__ bq, const float* __restrict__ bv,
           const float* __restrict__ bo,
           const float* __restrict__ b1, const float* __restrict__ b2,
           const float* __restrict__ g1, const float* __restrict__ be1,
           const float* __restrict__ g2, const float* __restrict__ be2,
           const short* __restrict__ wt, float* __restrict__ out) {
  extern __shared__ char sm[];
  char*  Cbuf = sm;                       // x tile (persistent) -> h
  char*  Tbuf = sm + 32768;               // dst -> src -> ctx -> hid -> out stage
  float* sc   = (float*)(sm + 65536);     // [4 waves][2 heads][64 rows] scores/weights
  float* scrP = (float*)(sm + 67584);     // LN partials [4 waves][64 rows][2]
  float* scrM = (float*)(sm + 69632);     // LN mean/rstd [64][2]

  const short* WqT = wt;
  const short* WkT = wt + 65536;
  const short* WvT = wt + 131072;
  const short* WoT = wt + 196608;
  const short* W1T = wt + 262144;
  const short* W2T = wt + 524288;

  const int tid  = threadIdx.x;
  const int w    = tid >> 6;              // 0..3
  const int lane = tid & 63;
  const int li   = lane & 15;
  const int hi   = lane >> 4;
  const int cw   = w * 64;                // wave col slice (2 heads)
  const size_t row0 = (size_t)blockIdx.x * BM;

  const float* xt = x  + row0 * 256;
  const float* st = sx + row0 * 256;
  const float* dt = dx + row0 * 256;

  float4 ld[16];

  // ---- P0: stage x -> Cbuf (persistent) ----
#pragma unroll
  for (int it = 0; it < 16; ++it) {
    int idx = it * THREADS + tid;
    ld[it] = *(const float4*)(xt + (idx >> 6) * 256 + ((idx & 63) << 2));
  }
#pragma unroll
  for (int it = 0; it < 16; ++it) {
    int idx = it * THREADS + tid;
    int r = idx >> 6, c = (idx & 63) << 2;
    s16x4 o;
    o[0] = f2bf(ld[it].x); o[1] = f2bf(ld[it].y);
    o[2] = f2bf(ld[it].z); o[3] = f2bf(ld[it].w);
    *(s16x4*)(Cbuf + swz(r, c)) = o;
  }
  __syncthreads();

  // ---- P1: issue dst loads; Q gemm (Cbuf); pack q->bf16; write dst->Tbuf ----
#pragma unroll
  for (int it = 0; it < 16; ++it) {
    int idx = it * THREADS + tid;
    ld[it] = *(const float4*)(dt + (idx >> 6) * 256 + ((idx & 63) << 2));
  }
  unsigned qb[4][4][2];
  {
    f32x4 qa[4][4];
#pragma unroll
    for (int m = 0; m < 4; ++m)
#pragma unroll
      for (int n = 0; n < 4; ++n) qa[m][n] = (f32x4){0.f, 0.f, 0.f, 0.f};
    gemmT<4, 4>(Cbuf, WqT, 256, cw, 0, li, hi, qa);
    const float scl = 0.17677669529663687f;
#pragma unroll
    for (int n = 0; n < 4; ++n) {
      float bqn = bq[cw + 16 * n + li] * scl;
#pragma unroll
      for (int m = 0; m < 4; ++m) {
        qb[m][n][0] = pack2(qa[m][n][0] + bqn, qa[m][n][1] + bqn);
        qb[m][n][1] = pack2(qa[m][n][2] + bqn, qa[m][n][3] + bqn);
      }
    }
  }
#pragma unroll
  for (int it = 0; it < 16; ++it) {
    int idx = it * THREADS + tid;
    int r = idx >> 6, c = (idx & 63) << 2;
    s16x4 o;
    o[0] = f2bf(ld[it].x); o[1] = f2bf(ld[it].y);
    o[2] = f2bf(ld[it].z); o[3] = f2bf(ld[it].w);
    *(s16x4*)(Tbuf + swz(r, c)) = o;
  }
  __syncthreads();

  // unpack packed q (compile-time indices in unrolled loops)
#define QF(m, n, j) bf2f((short)(((j) & 1) ? (qb[m][n][(j) >> 1] >> 16) \
                                           : (qb[m][n][(j) >> 1] & 0xffffu)))

  // ---- P2: issue src loads; K_dst scores; V_dst (held in regs) ----
#pragma unroll
  for (int it = 0; it < 16; ++it) {
    int idx = it * THREADS + tid;
    ld[it] = *(const float4*)(st + (idx >> 6) * 256 + ((idx & 63) << 2));
  }
#pragma unroll
  for (int hh = 0; hh < 2; ++hh) {
    f32x4 ka[4][2];
#pragma unroll
    for (int m = 0; m < 4; ++m)
#pragma unroll
      for (int n = 0; n < 2; ++n) ka[m][n] = (f32x4){0.f, 0.f, 0.f, 0.f};
    gemmT<4, 2>(Tbuf, WkT, 256, cw + 32 * hh, 0, li, hi, ka);
#pragma unroll
    for (int m = 0; m < 4; ++m)
#pragma unroll
      for (int j = 0; j < 4; ++j) {
        float pr = red16(QF(m, 2 * hh, j) * ka[m][0][j] +
                         QF(m, 2 * hh + 1, j) * ka[m][1][j]);
        if (li == 0) sc[(w * 2 + hh) * 64 + 16 * m + 4 * hi + j] = pr;
      }
  }
  f32x4 vd[4][4];
#pragma unroll
  for (int m = 0; m < 4; ++m)
#pragma unroll
    for (int n = 0; n < 4; ++n) vd[m][n] = (f32x4){0.f, 0.f, 0.f, 0.f};
  gemmT<4, 4>(Tbuf, WvT, 256, cw, 0, li, hi, vd);
  __syncthreads();                 // all waves done reading dst
#pragma unroll
  for (int it = 0; it < 16; ++it) {
    int idx = it * THREADS + tid;
    int r = idx >> 6, c = (idx & 63) << 2;
    s16x4 o;
    o[0] = f2bf(ld[it].x); o[1] = f2bf(ld[it].y);
    o[2] = f2bf(ld[it].z); o[3] = f2bf(ld[it].w);
    *(s16x4*)(Tbuf + swz(r, c)) = o;
  }
  __syncthreads();

  // ---- P3: K_src scores -> weights; V_src; combine; ctx -> Tbuf ----
#pragma unroll
  for (int hh = 0; hh < 2; ++hh) {
    f32x4 ka[4][2];
#pragma unroll
    for (int m = 0; m < 4; ++m)
#pragma unroll
      for (int n = 0; n < 2; ++n) ka[m][n] = (f32x4){0.f, 0.f, 0.f, 0.f};
    gemmT<4, 2>(Tbuf, WkT, 256, cw + 32 * hh, 0, li, hi, ka);
#pragma unroll
    for (int m = 0; m < 4; ++m)
#pragma unroll
      for (int j = 0; j < 4; ++j) {
        float ps = red16(QF(m, 2 * hh, j) * ka[m][0][j] +
                         QF(m, 2 * hh + 1, j) * ka[m][1][j]);
        int r = 16 * m + 4 * hi + j;
        float pdv = sc[(w * 2 + hh) * 64 + r];        // lockstep-safe
        float awv = 1.f / (1.f + expf(pdv - ps));      // weight on V_src
        if (li == 0) sc[(w * 2 + hh) * 64 + r] = awv;
      }
  }
  {
    f32x4 vs[4][4];
#pragma unroll
    for (int m = 0; m < 4; ++m)
#pragma unroll
      for (int n = 0; n < 4; ++n) vs[m][n] = (f32x4){0.f, 0.f, 0.f, 0.f};
    gemmT<4, 4>(Tbuf, WvT, 256, cw, 0, li, hi, vs);
#pragma unroll
    for (int hh = 0; hh < 2; ++hh)
#pragma unroll
      for (int n2 = 0; n2 < 2; ++n2) {
        int n = 2 * hh + n2;
        float bvn = bv[cw + 16 * n + li];
#pragma unroll
        for (int m = 0; m < 4; ++m)
#pragma unroll
          for (int j = 0; j < 4; ++j) {
            float a = sc[(w * 2 + hh) * 64 + 16 * m + 4 * hi + j];
            vs[m][n][j] = a * vs[m][n][j] + (1.f - a) * vd[m][n][j] + bvn;
          }
      }
    __syncthreads();               // all waves done reading src
#pragma unroll
    for (int m = 0; m < 4; ++m)
#pragma unroll
      for (int n = 0; n < 4; ++n)
#pragma unroll
        for (int j = 0; j < 4; ++j)
          *(short*)(Tbuf + swz(16 * m + 4 * hi + j, cw + 16 * n + li)) = f2bf(vs[m][n][j]);
  }
  __syncthreads();

  // ---- P4: O-proj + bo + x residual (Cbuf) + LN1 -> h into Cbuf ----
  {
    f32x4 oa[4][4];
#pragma unroll
    for (int m = 0; m < 4; ++m)
#pragma unroll
      for (int n = 0; n < 4; ++n) oa[m][n] = (f32x4){0.f, 0.f, 0.f, 0.f};
    gemmT<4, 4>(Tbuf, WoT, 256, cw, 0, li, hi, oa);
#pragma unroll
    for (int n = 0; n < 4; ++n) {
      float bon = bo[cw + 16 * n + li];
#pragma unroll
      for (int m = 0; m < 4; ++m)
#pragma unroll
        for (int j = 0; j < 4; ++j) {
          int r = 16 * m + 4 * hi + j;
          float xv = bf2f(*(short*)(Cbuf + swz(r, cw + 16 * n + li)));
          oa[m][n][j] += bon + xv;
        }
    }
#pragma unroll
    for (int m = 0; m < 4; ++m)
#pragma unroll
      for (int j = 0; j < 4; ++j) {
        int r = 16 * m + 4 * hi + j;
        float sv = oa[m][0][j] + oa[m][1][j] + oa[m][2][j] + oa[m][3][j];
        float qv = oa[m][0][j] * oa[m][0][j] + oa[m][1][j] * oa[m][1][j]
                 + oa[m][2][j] * oa[m][2][j] + oa[m][3][j] * oa[m][3][j];
        float s = red16(sv);
        float q = red16(qv);
        if (li == 0) { scrP[(w * 64 + r) * 2] = s; scrP[(w * 64 + r) * 2 + 1] = q; }
      }
    __syncthreads();
    if (tid < BM) {
      float S = 0.f, Q = 0.f;
#pragma unroll
      for (int ww = 0; ww < 4; ++ww) {
        S += scrP[(ww * 64 + tid) * 2];
        Q += scrP[(ww * 64 + tid) * 2 + 1];
      }
      float mean = S * (1.f / 256.f);
      float var  = Q * (1.f / 256.f) - mean * mean;
      scrM[tid * 2] = mean;
      scrM[tid * 2 + 1] = rsqrtf(var + 1e-5f);
    }
    __syncthreads();
#pragma unroll
    for (int n = 0; n < 4; ++n) {
      float g1n = g1[cw + 16 * n + li];
      float b1n = be1[cw + 16 * n + li];
#pragma unroll
      for (int m = 0; m < 4; ++m)
#pragma unroll
        for (int j = 0; j < 4; ++j) {
          int r = 16 * m + 4 * hi + j;
          float mean = scrM[r * 2], rs = scrM[r * 2 + 1];
          *(short*)(Cbuf + swz(r, cw + 16 * n + li)) =
              f2bf((oa[m][n][j] - mean) * rs * g1n + b1n);
        }
    }
  }
  __syncthreads();

  // ---- P5: FFN, 4 chunks of 256 hidden (W1 n-split, a2 accumulates) ----
  f32x4 a2[4][4];
#pragma unroll
  for (int m = 0; m < 4; ++m)
#pragma unroll
    for (int n = 0; n < 4; ++n) a2[m][n] = (f32x4){0.f, 0.f, 0.f, 0.f};
#pragma unroll 1
  for (int c = 0; c < 4; ++c) {
#pragma unroll
    for (int g = 0; g < 2; ++g) {
      f32x4 a1[4][2];
#pragma unroll
      for (int m = 0; m < 4; ++m)
#pragma unroll
        for (int n = 0; n < 2; ++n) a1[m][n] = (f32x4){0.f, 0.f, 0.f, 0.f};
      gemmT<4, 2>(Cbuf, W1T, 256, 256 * c + cw + 32 * g, 0, li, hi, a1);
#pragma unroll
      for (int n = 0; n < 2; ++n) {
        float b1n = b1[256 * c + cw + 32 * g + 16 * n + li];
#pragma unroll
        for (int m = 0; m < 4; ++m)
#pragma unroll
          for (int j = 0; j < 4; ++j) {
            int r = 16 * m + 4 * hi + j;
            *(short*)(Tbuf + swz(r, cw + 32 * g + 16 * n + li)) =
                f2bf(fmaxf(a1[m][n][j] + b1n, 0.f));
          }
      }
    }
    __syncthreads();
    gemmT<4, 4>(Tbuf, W2T, 1024, cw, 256 * c, li, hi, a2);
    __syncthreads();
  }

  // ---- P6: +b2 + h residual (Cbuf); LN2; store ----
  {
#pragma unroll
    for (int n = 0; n < 4; ++n) {
      float b2n = b2[cw + 16 * n + li];
#pragma unroll
      for (int m = 0; m < 4; ++m)
#pragma unroll
        for (int j = 0; j < 4; ++j) {
          int r = 16 * m + 4 * hi + j;
          a2[m][n][j] += b2n + bf2f(*(short*)(Cbuf + swz(r, cw + 16 * n + li)));
        }
    }
#pragma unroll
    for (int m = 0; m < 4; ++m)
#pragma unroll
      for (int j = 0; j < 4; ++j) {
        int r = 16 * m + 4 * hi + j;
        float sv = a2[m][0][j] + a2[m][1][j] + a2[m][2][j] + a2[m][3][j];
        float qv = a2[m][0][j] * a2[m][0][j] + a2[m][1][j] * a2[m][1][j]
                 + a2[m][2][j] * a2[m][2][j] + a2[m][3][j] * a2[m][3][j];
        float s = red16(sv);
        float q = red16(qv);
        if (li == 0) { scrP[(w * 64 + r) * 2] = s; scrP[(w * 64 + r) * 2 + 1] = q; }
      }
    __syncthreads();
    if (tid < BM) {
      float S = 0.f, Q = 0.f;
#pragma unroll
      for (int ww = 0; ww < 4; ++ww) {
        S += scrP[(ww * 64 + tid) * 2];
        Q += scrP[(ww * 64 + tid) * 2 + 1];
      }
      float mean = S * (1.f / 256.f);
      float var  = Q * (1.f / 256.f) - mean * mean;
      scrM[tid * 2] = mean;
      scrM[tid * 2 + 1] = rsqrtf(var + 1e-5f);
    }
    __syncthreads();

    float g2n[4], be2n[4];
#pragma unroll
    for (int n = 0; n < 4; ++n) {
      g2n[n] = g2[cw + 16 * n + li];
      be2n[n] = be2[cw + 16 * n + li];
    }
    float* orow = out + row0 * 256;
#pragma unroll
    for (int hf = 0; hf < 2; ++hf) {
#pragma unroll
      for (int m2 = 0; m2 < 2; ++m2) {
        int m = 2 * hf + m2;
#pragma unroll
        for (int n = 0; n < 4; ++n)
#pragma unroll
          for (int j = 0; j < 4; ++j) {
            int r = 16 * m + 4 * hi + j;
            float mean = scrM[r * 2], rs = scrM[r * 2 + 1];
            int rr = r - 32 * hf;
            *(float*)(Tbuf + rr * 1024 + (((cw + 16 * n + li) * 4) ^ ((rr & 7) << 4)))
                = (a2[m][n][j] - mean) * rs * g2n[n] + be2n[n];
          }
      }
      __syncthreads();
#pragma unroll
      for (int t = 0; t < 8; ++t) {
        int idx = t * THREADS + tid;           // 0..2047 float4 slots
        int r = idx >> 6, c4 = idx & 63;       // r 0..31
        f32x4 v = *(f32x4*)(Tbuf + r * 1024 + ((c4 * 16) ^ ((r & 7) << 4)));
        *(f32x4*)(orow + (hf * 32 + r) * 256 + c4 * 4) = v;
      }
      __syncthreads();
    }
  }
#undef QF
}

extern "C" void kernel_launch(void* const* d_in, const int* in_sizes, int n_in,
                              void* d_out, int out_size, void* d_ws, size_t ws_size,
                              hipStream_t stream) {
  const float* x   = (const float*)d_in[0];
  const float* sx  = (const float*)d_in[1];
  const float* dx  = (const float*)d_in[2];
  const float* Wq  = (const float*)d_in[3];
  const float* bq  = (const float*)d_in[4];
  const float* Wk  = (const float*)d_in[5];
  const float* Wv  = (const float*)d_in[7];
  const float* bv  = (const float*)d_in[8];
  const float* Wo  = (const float*)d_in[9];
  const float* bo  = (const float*)d_in[10];
  const float* W1  = (const float*)d_in[11];
  const float* b1  = (const float*)d_in[12];
  const float* W2  = (const float*)d_in[13];
  const float* b2  = (const float*)d_in[14];
  const float* g1  = (const float*)d_in[15];
  const float* be1 = (const float*)d_in[16];
  const float* g2  = (const float*)d_in[17];
  const float* be2 = (const float*)d_in[18];
  short* wt = (short*)d_ws;

  prep<<<dim3(1536), dim3(512), 0, stream>>>(Wq, Wk, Wv, Wo, W1, W2, wt);
  fused<<<dim3(NROWS / BM), dim3(THREADS), LDSB, stream>>>(
      x, sx, dx, bq, bv, bo, b1, b2, g1, be1, g2, be2, wt, (float*)d_out);
}

// Round 12
// 1081.588 us; speedup vs baseline: 1.6028x; 1.0018x over previous
//
#include <hip/hip_runtime.h>
#include <hip/hip_bf16.h>
#include <math.h>

#define NROWS   262144
#define BM      64
#define THREADS 256
// LDS: Cbuf 32K | Tbuf 32K | sc 2K | scrP 2K | scrM 512B
#define LDSB    (32768 + 32768 + 2048 + 2048 + 512)

using bf16x8 = __attribute__((ext_vector_type(8))) short;
using s16x4  = __attribute__((ext_vector_type(4))) short;
using f32x4  = __attribute__((ext_vector_type(4))) float;

__device__ __forceinline__ short f2bf(float f) {
  __hip_bfloat16 h = __float2bfloat16(f);
  return __builtin_bit_cast(short, h);
}
__device__ __forceinline__ float bf2f(short s) {
  __hip_bfloat16 h = __builtin_bit_cast(__hip_bfloat16, s);
  return __bfloat162float(h);
}
__device__ __forceinline__ unsigned pack2(float a, float b) {
  return (unsigned)(unsigned short)f2bf(a) | ((unsigned)(unsigned short)f2bf(b) << 16);
}
// XOR-swizzled byte offset into a [64][256] bf16 LDS tile (row stride 512B)
__device__ __forceinline__ int swz(int row, int col) {
  return row * 512 + ((col * 2) ^ ((row & 7) << 4));
}

__device__ __forceinline__ float red16(float p) {
  p += __shfl_xor(p, 1, 64);
  p += __shfl_xor(p, 2, 64);
  p += __shfl_xor(p, 4, 64);
  p += __shfl_xor(p, 8, 64);
  return p;
}

// C[64 rows x NF*16 cols] += A_lds[64 x 256] @ WT[cols][Kw] (B pre-transposed bf16)
template <int MF, int NF>
__device__ __forceinline__ void gemmT(const char* __restrict__ Abuf,
                                      const short* __restrict__ WT, int Kw,
                                      int col0, int koff, int li, int hi,
                                      f32x4 (&acc)[MF][NF]) {
  const short* wp[NF];
#pragma unroll
  for (int n = 0; n < NF; ++n)
    wp[n] = WT + (size_t)(col0 + 16 * n + li) * Kw + koff + hi * 8;
#pragma unroll 2
  for (int kk = 0; kk < 256; kk += 32) {
    int ka = kk + hi * 8;
    bf16x8 b[NF];
#pragma unroll
    for (int n = 0; n < NF; ++n) b[n] = *(const bf16x8*)(wp[n] + kk);
    bf16x8 a[MF];
#pragma unroll
    for (int m = 0; m < MF; ++m)
      a[m] = *(const bf16x8*)(Abuf + swz(16 * m + li, ka));
#pragma unroll
    for (int m = 0; m < MF; ++m)
#pragma unroll
      for (int n = 0; n < NF; ++n)
        acc[m][n] = __builtin_amdgcn_mfma_f32_16x16x32_bf16(a[m], b[n], acc[m][n], 0, 0, 0);
  }
}

// transpose + bf16-convert all weights (Wq pre-scaled by 1/sqrt(DH)):
// WqT,WkT,WvT,WoT: [256][256]; W1T: [1024][256]; W2T: [256][1024]
__global__ void prep(const float* __restrict__ Wq, const float* __restrict__ Wk,
                     const float* __restrict__ Wv, const float* __restrict__ Wo,
                     const float* __restrict__ W1, const float* __restrict__ W2,
                     short* __restrict__ wt) {
  int idx = blockIdx.x * blockDim.x + threadIdx.x;  // 0..786431
  if (idx < 262144) {
    int m = idx >> 16;
    const float* W = (m == 0) ? Wq : (m == 1) ? Wk : (m == 2) ? Wv : Wo;
    float s = (m == 0) ? 0.17677669529663687f : 1.0f;
    int l = idx & 65535;
    int n = l >> 8, k = l & 255;
    wt[idx] = f2bf(W[k * 256 + n] * s);
  } else if (idx < 524288) {
    int l = idx - 262144;
    int n = l >> 8, k = l & 255;
    wt[idx] = f2bf(W1[k * 1024 + n]);
  } else {
    int l = idx - 524288;
    int n = l >> 10, k = l & 1023;
    wt[idx] = f2bf(W2[k * 256 + n]);
  }
}

// ================= fused: attention + LN1 + FFN + LN2 =================
__global__ __launch_bounds__(THREADS, 2)
void fused(const float* __restrict__ x, const float* __restrict__ sx,
           const float* __restrict__ dx,
           const float* __restrict__ bq, const float* __restrict__ bv,
           const float* __restrict__ bo,
           const float* __restrict__ b1, const float* __restrict__ b2,
           const float* __restrict__ g1, const float* __restrict__ be1,
           const float* __restrict__ g2, const float* __restrict__ be2,
           const short* __restrict__ wt, float* __restrict__ out) {
  extern __shared__ char sm[];
  char*  Cbuf = sm;                       // x tile (persistent) -> h
  char*  Tbuf = sm + 32768;               // dst -> src -> ctx -> hid -> out stage
  float* sc   = (float*)(sm + 65536);     // [4 waves][2 heads][64 rows] scores/weights
  float* scrP = (float*)(sm + 67584);     // LN partials [4 waves][64 rows][2]
  float* scrM = (float*)(sm + 69632);     // LN mean/rstd [64][2]

  const short* WqT = wt;
  const short* WkT = wt + 65536;
  const short* WvT = wt + 131072;
  const short* WoT = wt + 196608;
  const short* W1T = wt + 262144;
  const short* W2T = wt + 524288;

  const int tid  = threadIdx.x;
  const int w    = tid >> 6;              // 0..3
  const int lane = tid & 63;
  const int li   = lane & 15;
  const int hi   = lane >> 4;
  const int cw   = w * 64;                // wave col slice (2 heads)
  const size_t row0 = (size_t)blockIdx.x * BM;

  const float* xt = x  + row0 * 256;
  const float* st = sx + row0 * 256;
  const float* dt = dx + row0 * 256;

  float4 ld[16];

  // ---- P0: stage x -> Cbuf (persistent) ----
#pragma unroll
  for (int it = 0; it < 16; ++it) {
    int idx = it * THREADS + tid;
    ld[it] = *(const float4*)(xt + (idx >> 6) * 256 + ((idx & 63) << 2));
  }
#pragma unroll
  for (int it = 0; it < 16; ++it) {
    int idx = it * THREADS + tid;
    int r = idx >> 6, c = (idx & 63) << 2;
    s16x4 o;
    o[0] = f2bf(ld[it].x); o[1] = f2bf(ld[it].y);
    o[2] = f2bf(ld[it].z); o[3] = f2bf(ld[it].w);
    *(s16x4*)(Cbuf + swz(r, c)) = o;
  }
  __syncthreads();

  // ---- P1: issue dst loads; Q gemm (Cbuf); pack q->bf16; write dst->Tbuf ----
#pragma unroll
  for (int it = 0; it < 16; ++it) {
    int idx = it * THREADS + tid;
    ld[it] = *(const float4*)(dt + (idx >> 6) * 256 + ((idx & 63) << 2));
  }
  unsigned qb[4][4][2];
  {
    f32x4 qa[4][4];
#pragma unroll
    for (int m = 0; m < 4; ++m)
#pragma unroll
      for (int n = 0; n < 4; ++n) qa[m][n] = (f32x4){0.f, 0.f, 0.f, 0.f};
    gemmT<4, 4>(Cbuf, WqT, 256, cw, 0, li, hi, qa);
    const float scl = 0.17677669529663687f;
#pragma unroll
    for (int n = 0; n < 4; ++n) {
      float bqn = bq[cw + 16 * n + li] * scl;
#pragma unroll
      for (int m = 0; m < 4; ++m) {
        qb[m][n][0] = pack2(qa[m][n][0] + bqn, qa[m][n][1] + bqn);
        qb[m][n][1] = pack2(qa[m][n][2] + bqn, qa[m][n][3] + bqn);
      }
    }
  }
#pragma unroll
  for (int it = 0; it < 16; ++it) {
    int idx = it * THREADS + tid;
    int r = idx >> 6, c = (idx & 63) << 2;
    s16x4 o;
    o[0] = f2bf(ld[it].x); o[1] = f2bf(ld[it].y);
    o[2] = f2bf(ld[it].z); o[3] = f2bf(ld[it].w);
    *(s16x4*)(Tbuf + swz(r, c)) = o;
  }
  __syncthreads();

  // unpack helpers (compile-time indices in unrolled loops)
#define QF(m, n, j) bf2f((short)(((j) & 1) ? (qb[m][n][(j) >> 1] >> 16) \
                                           : (qb[m][n][(j) >> 1] & 0xffffu)))
#define VF(m, n, j) bf2f((short)(((j) & 1) ? (vdb[m][n][(j) >> 1] >> 16) \
                                           : (vdb[m][n][(j) >> 1] & 0xffffu)))

  // ---- P2: issue src loads; K_dst scores; V_dst gemm -> packed bf16 ----
#pragma unroll
  for (int it = 0; it < 16; ++it) {
    int idx = it * THREADS + tid;
    ld[it] = *(const float4*)(st + (idx >> 6) * 256 + ((idx & 63) << 2));
  }
#pragma unroll
  for (int hh = 0; hh < 2; ++hh) {
    f32x4 ka[4][2];
#pragma unroll
    for (int m = 0; m < 4; ++m)
#pragma unroll
      for (int n = 0; n < 2; ++n) ka[m][n] = (f32x4){0.f, 0.f, 0.f, 0.f};
    gemmT<4, 2>(Tbuf, WkT, 256, cw + 32 * hh, 0, li, hi, ka);
#pragma unroll
    for (int m = 0; m < 4; ++m)
#pragma unroll
      for (int j = 0; j < 4; ++j) {
        float pr = red16(QF(m, 2 * hh, j) * ka[m][0][j] +
                         QF(m, 2 * hh + 1, j) * ka[m][1][j]);
        if (li == 0) sc[(w * 2 + hh) * 64 + 16 * m + 4 * hi + j] = pr;
      }
  }
  unsigned vdb[4][4][2];
  {
    f32x4 vd[4][4];
#pragma unroll
    for (int m = 0; m < 4; ++m)
#pragma unroll
      for (int n = 0; n < 4; ++n) vd[m][n] = (f32x4){0.f, 0.f, 0.f, 0.f};
    gemmT<4, 4>(Tbuf, WvT, 256, cw, 0, li, hi, vd);
    // pack to bf16 immediately: frees 64 AGPRs before the src phase
#pragma unroll
    for (int m = 0; m < 4; ++m)
#pragma unroll
      for (int n = 0; n < 4; ++n) {
        vdb[m][n][0] = pack2(vd[m][n][0], vd[m][n][1]);
        vdb[m][n][1] = pack2(vd[m][n][2], vd[m][n][3]);
      }
  }
  __syncthreads();                 // all waves done reading dst
#pragma unroll
  for (int it = 0; it < 16; ++it) {
    int idx = it * THREADS + tid;
    int r = idx >> 6, c = (idx & 63) << 2;
    s16x4 o;
    o[0] = f2bf(ld[it].x); o[1] = f2bf(ld[it].y);
    o[2] = f2bf(ld[it].z); o[3] = f2bf(ld[it].w);
    *(s16x4*)(Tbuf + swz(r, c)) = o;
  }
  __syncthreads();

  // ---- P3: K_src scores -> weights; V_src; combine; ctx -> Tbuf ----
#pragma unroll
  for (int hh = 0; hh < 2; ++hh) {
    f32x4 ka[4][2];
#pragma unroll
    for (int m = 0; m < 4; ++m)
#pragma unroll
      for (int n = 0; n < 2; ++n) ka[m][n] = (f32x4){0.f, 0.f, 0.f, 0.f};
    gemmT<4, 2>(Tbuf, WkT, 256, cw + 32 * hh, 0, li, hi, ka);
#pragma unroll
    for (int m = 0; m < 4; ++m)
#pragma unroll
      for (int j = 0; j < 4; ++j) {
        float ps = red16(QF(m, 2 * hh, j) * ka[m][0][j] +
                         QF(m, 2 * hh + 1, j) * ka[m][1][j]);
        int r = 16 * m + 4 * hi + j;
        float pdv = sc[(w * 2 + hh) * 64 + r];        // lockstep-safe
        float awv = 1.f / (1.f + expf(pdv - ps));      // weight on V_src
        if (li == 0) sc[(w * 2 + hh) * 64 + r] = awv;
      }
  }
  {
    f32x4 vs[4][4];
#pragma unroll
    for (int m = 0; m < 4; ++m)
#pragma unroll
      for (int n = 0; n < 4; ++n) vs[m][n] = (f32x4){0.f, 0.f, 0.f, 0.f};
    gemmT<4, 4>(Tbuf, WvT, 256, cw, 0, li, hi, vs);
#pragma unroll
    for (int hh = 0; hh < 2; ++hh)
#pragma unroll
      for (int n2 = 0; n2 < 2; ++n2) {
        int n = 2 * hh + n2;
        float bvn = bv[cw + 16 * n + li];
#pragma unroll
        for (int m = 0; m < 4; ++m)
#pragma unroll
          for (int j = 0; j < 4; ++j) {
            float a = sc[(w * 2 + hh) * 64 + 16 * m + 4 * hi + j];
            vs[m][n][j] = a * vs[m][n][j] + (1.f - a) * VF(m, n, j) + bvn;
          }
      }
    __syncthreads();               // all waves done reading src
#pragma unroll
    for (int m = 0; m < 4; ++m)
#pragma unroll
      for (int n = 0; n < 4; ++n)
#pragma unroll
        for (int j = 0; j < 4; ++j)
          *(short*)(Tbuf + swz(16 * m + 4 * hi + j, cw + 16 * n + li)) = f2bf(vs[m][n][j]);
  }
  __syncthreads();

  // ---- P4: O-proj + bo + x residual (Cbuf) + LN1 -> h into Cbuf ----
  {
    f32x4 oa[4][4];
#pragma unroll
    for (int m = 0; m < 4; ++m)
#pragma unroll
      for (int n = 0; n < 4; ++n) oa[m][n] = (f32x4){0.f, 0.f, 0.f, 0.f};
    gemmT<4, 4>(Tbuf, WoT, 256, cw, 0, li, hi, oa);
#pragma unroll
    for (int n = 0; n < 4; ++n) {
      float bon = bo[cw + 16 * n + li];
#pragma unroll
      for (int m = 0; m < 4; ++m)
#pragma unroll
        for (int j = 0; j < 4; ++j) {
          int r = 16 * m + 4 * hi + j;
          float xv = bf2f(*(short*)(Cbuf + swz(r, cw + 16 * n + li)));
          oa[m][n][j] += bon + xv;
        }
    }
#pragma unroll
    for (int m = 0; m < 4; ++m)
#pragma unroll
      for (int j = 0; j < 4; ++j) {
        int r = 16 * m + 4 * hi + j;
        float sv = oa[m][0][j] + oa[m][1][j] + oa[m][2][j] + oa[m][3][j];
        float qv = oa[m][0][j] * oa[m][0][j] + oa[m][1][j] * oa[m][1][j]
                 + oa[m][2][j] * oa[m][2][j] + oa[m][3][j] * oa[m][3][j];
        float s = red16(sv);
        float q = red16(qv);
        if (li == 0) { scrP[(w * 64 + r) * 2] = s; scrP[(w * 64 + r) * 2 + 1] = q; }
      }
    __syncthreads();
    if (tid < BM) {
      float S = 0.f, Q = 0.f;
#pragma unroll
      for (int ww = 0; ww < 4; ++ww) {
        S += scrP[(ww * 64 + tid) * 2];
        Q += scrP[(ww * 64 + tid) * 2 + 1];
      }
      float mean = S * (1.f / 256.f);
      float var  = Q * (1.f / 256.f) - mean * mean;
      scrM[tid * 2] = mean;
      scrM[tid * 2 + 1] = rsqrtf(var + 1e-5f);
    }
    __syncthreads();
#pragma unroll
    for (int n = 0; n < 4; ++n) {
      float g1n = g1[cw + 16 * n + li];
      float b1n = be1[cw + 16 * n + li];
#pragma unroll
      for (int m = 0; m < 4; ++m)
#pragma unroll
        for (int j = 0; j < 4; ++j) {
          int r = 16 * m + 4 * hi + j;
          float mean = scrM[r * 2], rs = scrM[r * 2 + 1];
          *(short*)(Cbuf + swz(r, cw + 16 * n + li)) =
              f2bf((oa[m][n][j] - mean) * rs * g1n + b1n);
        }
    }
  }
  __syncthreads();

  // ---- P5: FFN, 4 chunks of 256 hidden (W1 n-split, a2 accumulates) ----
  f32x4 a2[4][4];
#pragma unroll
  for (int m = 0; m < 4; ++m)
#pragma unroll
    for (int n = 0; n < 4; ++n) a2[m][n] = (f32x4){0.f, 0.f, 0.f, 0.f};
#pragma unroll 1
  for (int c = 0; c < 4; ++c) {
#pragma unroll
    for (int g = 0; g < 2; ++g) {
      f32x4 a1[4][2];
#pragma unroll
      for (int m = 0; m < 4; ++m)
#pragma unroll
        for (int n = 0; n < 2; ++n) a1[m][n] = (f32x4){0.f, 0.f, 0.f, 0.f};
      gemmT<4, 2>(Cbuf, W1T, 256, 256 * c + cw + 32 * g, 0, li, hi, a1);
#pragma unroll
      for (int n = 0; n < 2; ++n) {
        float b1n = b1[256 * c + cw + 32 * g + 16 * n + li];
#pragma unroll
        for (int m = 0; m < 4; ++m)
#pragma unroll
          for (int j = 0; j < 4; ++j) {
            int r = 16 * m + 4 * hi + j;
            *(short*)(Tbuf + swz(r, cw + 32 * g + 16 * n + li)) =
                f2bf(fmaxf(a1[m][n][j] + b1n, 0.f));
          }
      }
    }
    __syncthreads();
    gemmT<4, 4>(Tbuf, W2T, 1024, cw, 256 * c, li, hi, a2);
    __syncthreads();
  }

  // ---- P6: +b2 + h residual (Cbuf); LN2; store ----
  {
#pragma unroll
    for (int n = 0; n < 4; ++n) {
      float b2n = b2[cw + 16 * n + li];
#pragma unroll
      for (int m = 0; m < 4; ++m)
#pragma unroll
        for (int j = 0; j < 4; ++j) {
          int r = 16 * m + 4 * hi + j;
          a2[m][n][j] += b2n + bf2f(*(short*)(Cbuf + swz(r, cw + 16 * n + li)));
        }
    }
#pragma unroll
    for (int m = 0; m < 4; ++m)
#pragma unroll
      for (int j = 0; j < 4; ++j) {
        int r = 16 * m + 4 * hi + j;
        float sv = a2[m][0][j] + a2[m][1][j] + a2[m][2][j] + a2[m][3][j];
        float qv = a2[m][0][j] * a2[m][0][j] + a2[m][1][j] * a2[m][1][j]
                 + a2[m][2][j] * a2[m][2][j] + a2[m][3][j] * a2[m][3][j];
        float s = red16(sv);
        float q = red16(qv);
        if (li == 0) { scrP[(w * 64 + r) * 2] = s; scrP[(w * 64 + r) * 2 + 1] = q; }
      }
    __syncthreads();
    if (tid < BM) {
      float S = 0.f, Q = 0.f;
#pragma unroll
      for (int ww = 0; ww < 4; ++ww) {
        S += scrP[(ww * 64 + tid) * 2];
        Q += scrP[(ww * 64 + tid) * 2 + 1];
      }
      float mean = S * (1.f / 256.f);
      float var  = Q * (1.f / 256.f) - mean * mean;
      scrM[tid * 2] = mean;
      scrM[tid * 2 + 1] = rsqrtf(var + 1e-5f);
    }
    __syncthreads();

    float g2n[4], be2n[4];
#pragma unroll
    for (int n = 0; n < 4; ++n) {
      g2n[n] = g2[cw + 16 * n + li];
      be2n[n] = be2[cw + 16 * n + li];
    }
    float* orow = out + row0 * 256;
#pragma unroll
    for (int hf = 0; hf < 2; ++hf) {
#pragma unroll
      for (int m2 = 0; m2 < 2; ++m2) {
        int m = 2 * hf + m2;
#pragma unroll
        for (int n = 0; n < 4; ++n)
#pragma unroll
          for (int j = 0; j < 4; ++j) {
            int r = 16 * m + 4 * hi + j;
            float mean = scrM[r * 2], rs = scrM[r * 2 + 1];
            int rr = r - 32 * hf;
            *(float*)(Tbuf + rr * 1024 + (((cw + 16 * n + li) * 4) ^ ((rr & 7) << 4)))
                = (a2[m][n][j] - mean) * rs * g2n[n] + be2n[n];
          }
      }
      __syncthreads();
#pragma unroll
      for (int t = 0; t < 8; ++t) {
        int idx = t * THREADS + tid;           // 0..2047 float4 slots
        int r = idx >> 6, c4 = idx & 63;       // r 0..31
        f32x4 v = *(f32x4*)(Tbuf + r * 1024 + ((c4 * 16) ^ ((r & 7) << 4)));
        *(f32x4*)(orow + (hf * 32 + r) * 256 + c4 * 4) = v;
      }
      __syncthreads();
    }
  }
#undef QF
#undef VF
}

extern "C" void kernel_launch(void* const* d_in, const int* in_sizes, int n_in,
                              void* d_out, int out_size, void* d_ws, size_t ws_size,
                              hipStream_t stream) {
  const float* x   = (const float*)d_in[0];
  const float* sx  = (const float*)d_in[1];
  const float* dx  = (const float*)d_in[2];
  const float* Wq  = (const float*)d_in[3];
  const float* bq  = (const float*)d_in[4];
  const float* Wk  = (const float*)d_in[5];
  const float* Wv  = (const float*)d_in[7];
  const float* bv  = (const float*)d_in[8];
  const float* Wo  = (const float*)d_in[9];
  const float* bo  = (const float*)d_in[10];
  const float* W1  = (const float*)d_in[11];
  const float* b1  = (const float*)d_in[12];
  const float* W2  = (const float*)d_in[13];
  const float* b2  = (const float*)d_in[14];
  const float* g1  = (const float*)d_in[15];
  const float* be1 = (const float*)d_in[16];
  const float* g2  = (const float*)d_in[17];
  const float* be2 = (const float*)d_in[18];
  short* wt = (short*)d_ws;

  prep<<<dim3(1536), dim3(512), 0, stream>>>(Wq, Wk, Wv, Wo, W1, W2, wt);
  fused<<<dim3(NROWS / BM), dim3(THREADS), LDSB, stream>>>(
      x, sx, dx, bq, bv, bo, b1, b2, g1, be1, g2, be2, wt, (float*)d_out);
}